// Round 1
// baseline (579.397 us; speedup 1.0000x reference)
//
#include <hip/hip_runtime.h>
#include <hip/hip_bf16.h>

#define BATCH 16384

typedef __attribute__((ext_vector_type(4))) float f32x4;
typedef __attribute__((ext_vector_type(8))) short bf16x8;

__device__ inline float b2f(unsigned short u) {
    union { unsigned u; float f; } c; c.u = ((unsigned)u) << 16; return c.f;
}
__device__ inline unsigned short f2b(float f) {
    __hip_bfloat16 h = __float2bfloat16(f);
    return *(unsigned short*)&h;
}

// ---------------- weight prep: f32 (K x N) -> bf16 transposed (N x K) ----------------
__global__ void k_transpose_cvt(const float* __restrict__ src, int K, int N,
                                unsigned short* __restrict__ dst, int dst_off, int dst_ld)
{
    __shared__ float t[32][33];
    int k0 = blockIdx.y * 32, n0 = blockIdx.x * 32;
    int tx = threadIdx.x, ty = threadIdx.y; // 32 x 8
    #pragma unroll
    for (int s = 0; s < 32; s += 8) {
        int k = k0 + ty + s, n = n0 + tx;
        t[ty + s][tx] = (k < K && n < N) ? src[(size_t)k * N + n] : 0.f;
    }
    __syncthreads();
    #pragma unroll
    for (int s = 0; s < 32; s += 8) {
        int n = n0 + ty + s, k = k0 + tx;
        if (n < N && k < K)
            dst[(size_t)(dst_off + n) * dst_ld + k] = f2b(t[tx][ty + s]);
    }
}

__global__ void k_copyf(const float* __restrict__ src, float* __restrict__ dst, int n) {
    int i = blockIdx.x * 256 + threadIdx.x;
    if (i < n) dst[i] = src[i];
}
__global__ void k_zerof(float* __restrict__ dst, int n) {
    int i = blockIdx.x * 256 + threadIdx.x;
    if (i < n) dst[i] = 0.f;
}

// ---------------- embedding gather -> bf16 x_emb (B, 2048) ----------------
__global__ __launch_bounds__(256) void k_gather(const int* __restrict__ x,
                                                const float* __restrict__ emb,
                                                unsigned short* __restrict__ Xemb)
{
    int i = blockIdx.x * 256 + threadIdx.x;   // group of 4 elements
    int b  = i >> 9;                          // 512 groups per row of 2048
    int j4 = (i & 511) << 2;
    int f  = j4 >> 6;
    int l  = j4 & 63;
    int idx = x[b * 32 + f];
    float4 v = *(const float4*)(emb + (size_t)idx * 64 + l);
    ushort4 o;
    o.x = f2b(v.x); o.y = f2b(v.y); o.z = f2b(v.z); o.w = f2b(v.w);
    *(ushort4*)(Xemb + (size_t)b * 2048 + j4) = o;
}

// ---------------- bf16 MFMA GEMM: C(MxN) = A(MxK) * Bt(NxK)^T + bias, opt relu ----------------
// M is implicit (grid.y*128), always multiple of 128. K multiple of 32. N masked.
template<int RELU, int OUTBF16>
__global__ __launch_bounds__(256) void k_gemm(
    const unsigned short* __restrict__ A, int lda,
    const unsigned short* __restrict__ Bt,         // N x K row-major, ldb = K
    const float* __restrict__ bias,
    void* __restrict__ C, int ldc,
    int N, int K)
{
    __shared__ __align__(16) unsigned short As[128 * 40];  // pad 32 -> 40 elems/row
    __shared__ __align__(16) unsigned short Bs[128 * 40];
    const int tid  = threadIdx.x;
    const int lane = tid & 63;
    const int w    = tid >> 6;
    const int wr   = w >> 1, wc = w & 1;
    const int row0 = blockIdx.y * 128;
    const int col0 = blockIdx.x * 128;
    const int frow = lane & 15;
    const int kg   = lane >> 4;      // k-group 0..3 (k offset kg*8)
    const int r0   = tid >> 2;       // staging row 0..63 (and +64)
    const int kc   = tid & 3;        // staging k-chunk

    f32x4 acc[4][4] = {};

    for (int bk = 0; bk < K; bk += 32) {
        __syncthreads();
        {
            uint4 va = *(const uint4*)(A + (size_t)(row0 + r0) * lda + bk + kc * 8);
            uint4 vb = *(const uint4*)(A + (size_t)(row0 + r0 + 64) * lda + bk + kc * 8);
            *(uint4*)&As[r0 * 40 + kc * 8]        = va;
            *(uint4*)&As[(r0 + 64) * 40 + kc * 8] = vb;
            uint4 z = {0, 0, 0, 0};
            uint4 wa = (col0 + r0 < N)      ? *(const uint4*)(Bt + (size_t)(col0 + r0) * K + bk + kc * 8)      : z;
            uint4 wb = (col0 + r0 + 64 < N) ? *(const uint4*)(Bt + (size_t)(col0 + r0 + 64) * K + bk + kc * 8) : z;
            *(uint4*)&Bs[r0 * 40 + kc * 8]        = wa;
            *(uint4*)&Bs[(r0 + 64) * 40 + kc * 8] = wb;
        }
        __syncthreads();
        bf16x8 af[4], bf_[4];
        #pragma unroll
        for (int m = 0; m < 4; ++m)
            af[m] = *(const bf16x8*)&As[(wr * 64 + m * 16 + frow) * 40 + kg * 8];
        #pragma unroll
        for (int n = 0; n < 4; ++n)
            bf_[n] = *(const bf16x8*)&Bs[(wc * 64 + n * 16 + frow) * 40 + kg * 8];
        #pragma unroll
        for (int m = 0; m < 4; ++m)
            #pragma unroll
            for (int n = 0; n < 4; ++n)
                acc[m][n] = __builtin_amdgcn_mfma_f32_16x16x32_bf16(af[m], bf_[n], acc[m][n], 0, 0, 0);
    }

    // epilogue: C/D layout col=lane&15, row=(lane>>4)*4+reg   [m89-verified]
    #pragma unroll
    for (int n = 0; n < 4; ++n) {
        int gcol = col0 + wc * 64 + n * 16 + frow;
        if (gcol >= N) continue;
        float bv = bias[gcol];
        #pragma unroll
        for (int m = 0; m < 4; ++m) {
            int gr = row0 + wr * 64 + m * 16 + kg * 4;
            #pragma unroll
            for (int r = 0; r < 4; ++r) {
                float v = acc[m][n][r] + bv;
                if (RELU) v = fmaxf(v, 0.f);
                size_t idx = (size_t)(gr + r) * ldc + gcol;
                if (OUTBF16) ((unsigned short*)C)[idx] = f2b(v);
                else         ((float*)C)[idx] = v;
            }
        }
    }
}

// ---------------- per-sample domain LoRA: lora = (x@DA0[d])@DB0[d]+Dlb0[d]; ddnn=relu(share+lora) ----------------
__global__ __launch_bounds__(256) void k_dlora(
    const unsigned short* __restrict__ Xdnn, const int* __restrict__ d,
    const float* __restrict__ DA0, const float* __restrict__ DB0, const float* __restrict__ Dlb0,
    const unsigned short* __restrict__ SHARE,
    unsigned short* __restrict__ LORA, unsigned short* __restrict__ DDNN)
{
    int w = threadIdx.x >> 6, lane = threadIdx.x & 63;
    int b = blockIdx.x * 4 + w;
    int dom = d[b];
    uint4 raw = *(const uint4*)(Xdnn + (size_t)b * 512 + lane * 8);
    const unsigned short* pr = (const unsigned short*)&raw;
    float xv[8];
    #pragma unroll
    for (int j = 0; j < 8; ++j) xv[j] = b2f(pr[j]);

    const float* Ap = DA0 + ((size_t)dom * 512 + lane * 8) * 16;
    float v[16];
    #pragma unroll
    for (int r = 0; r < 16; ++r) v[r] = 0.f;
    #pragma unroll
    for (int j = 0; j < 8; ++j) {
        float xj = xv[j];
        #pragma unroll
        for (int r = 0; r < 16; ++r) v[r] += xj * Ap[j * 16 + r];
    }
    #pragma unroll
    for (int s = 1; s < 64; s <<= 1) {
        #pragma unroll
        for (int r = 0; r < 16; ++r) v[r] += __shfl_xor(v[r], s, 64);
    }
    const float* Bp  = DB0 + (size_t)dom * 16 * 256;
    const float* lbp = Dlb0 + (size_t)dom * 256;
    #pragma unroll
    for (int c = 0; c < 4; ++c) {
        int o = lane + c * 64;
        float a = lbp[o];
        #pragma unroll
        for (int r = 0; r < 16; ++r) a += v[r] * Bp[r * 256 + o];
        float sh = b2f(SHARE[(size_t)b * 256 + o]);
        LORA[(size_t)b * 256 + o] = f2b(a);
        DDNN[(size_t)b * 256 + o] = f2b(fmaxf(sh + a, 0.f));
    }
}

// ---------------- fused tail: task-0 LoRA expansion, i=1 collapse, gates, output ----------------
__global__ __launch_bounds__(256) void k_tail(
    const float* __restrict__ Yd, const float* __restrict__ Ys, const float* __restrict__ Yl,
    const unsigned short* __restrict__ Hyper,
    const float* __restrict__ TB0, const float* __restrict__ Tlb0,
    const float* __restrict__ Tk1, const float* __restrict__ Tb1,
    const float* __restrict__ TA1, const float* __restrict__ TB1, const float* __restrict__ Tlb1,
    const float* __restrict__ h0W, const float* __restrict__ h0b,
    const float* __restrict__ h1W, const float* __restrict__ h1b,
    float* __restrict__ out)
{
    __shared__ float sTB0[2][16][128];
    __shared__ float sTlb0[2][128];
    __shared__ float sTk1[128];
    __shared__ float sWeff[2][128];
    __shared__ float sY[4][3][160];
    const int tid = threadIdx.x;

    for (int i = tid; i < 4096; i += 256) ((float*)sTB0)[i] = TB0[i];
    if (tid < 256) ((float*)sTlb0)[tid] = Tlb0[tid];
    if (tid < 128) sTk1[tid] = Tk1[tid];
    {
        int t = tid >> 7, j = tid & 127;
        float a = 0.f;
        #pragma unroll
        for (int r = 0; r < 16; ++r) a += TA1[((size_t)t * 128 + j) * 16 + r] * TB1[t * 16 + r];
        sWeff[t][j] = a;  // TA1[t] . TB1[t]  (collapsed rank-16 path)
    }
    const float* Yp[3] = {Yd, Ys, Yl};
    int b0 = blockIdx.x * 4;
    for (int i = tid; i < 4 * 3 * 160; i += 256) {
        int s = i / 480, rem = i % 480, st = rem / 160, idx = rem % 160;
        sY[s][st][idx] = Yp[st][(size_t)(b0 + s) * 160 + idx];
    }
    __syncthreads();

    int w = tid >> 6, lane = tid & 63;
    int b = b0 + w;
    const float* yd = sY[w][0];
    const float* ys = sY[w][1];
    const float* yl = sY[w][2];
    int j0 = lane, j1 = lane + 64;

    // gate partials: hyper[b] . h{0,1}W
    uint4 hraw = *(const uint4*)(Hyper + (size_t)b * 512 + lane * 8);
    const unsigned short* hp = (const unsigned short*)&hraw;
    float hv[8];
    #pragma unroll
    for (int j = 0; j < 8; ++j) hv[j] = b2f(hp[j]);

    float red[14];
    #pragma unroll
    for (int k = 0; k < 14; ++k) red[k] = 0.f;
    #pragma unroll
    for (int j = 0; j < 8; ++j) {
        float4 w0 = *(const float4*)(h0W + (size_t)(lane * 8 + j) * 4);
        float4 w1 = *(const float4*)(h1W + (size_t)(lane * 8 + j) * 4);
        red[0] += hv[j] * w0.x; red[1] += hv[j] * w0.y; red[2] += hv[j] * w0.z; red[3] += hv[j] * w0.w;
        red[4] += hv[j] * w1.x; red[5] += hv[j] * w1.y; red[6] += hv[j] * w1.z; red[7] += hv[j] * w1.w;
    }

    float SLv[2][2], LSv[2][2];
    #pragma unroll
    for (int t = 0; t < 2; ++t) {
        float lb0 = sTlb0[t][j0], lb1 = sTlb0[t][j1];
        float dl0 = lb0, dl1 = lb1, sl0 = lb0, sl1 = lb1, ll0 = lb0, ll1 = lb1;
        #pragma unroll
        for (int r = 0; r < 16; ++r) {
            float w0v = sTB0[t][r][j0], w1v = sTB0[t][r][j1];
            float ud = yd[128 + t * 16 + r];
            float us = ys[128 + t * 16 + r];
            float ul = yl[128 + t * 16 + r];
            dl0 += ud * w0v; dl1 += ud * w1v;
            sl0 += us * w0v; sl1 += us * w1v;
            ll0 += ul * w0v; ll1 += ul * w1v;
        }
        float D0 = yd[j0] + dl0, D1 = yd[j1] + dl1;   // ds + dl
        float S0 = ys[j0],       S1 = ys[j1];         // ss
        float L0 = ll0,          L1 = ll1;            // ll
        float sl_0 = sl0, sl_1 = sl1;                 // sl
        float ls_0 = yl[j0], ls_1 = yl[j1];           // ls
        if (t == 0) {  // relu fires only at (i=0, t=0)
            D0 = fmaxf(D0, 0.f); D1 = fmaxf(D1, 0.f);
            S0 = fmaxf(S0, 0.f); S1 = fmaxf(S1, 0.f);
            L0 = fmaxf(L0, 0.f); L1 = fmaxf(L1, 0.f);
            sl_0 = fmaxf(sl_0, 0.f); sl_1 = fmaxf(sl_1, 0.f);
            ls_0 = fmaxf(ls_0, 0.f); ls_1 = fmaxf(ls_1, 0.f);
        }
        SLv[t][0] = sl_0; SLv[t][1] = sl_1;
        LSv[t][0] = ls_0; LSv[t][1] = ls_1;
        float we0 = sWeff[t][j0], we1 = sWeff[t][j1];
        float tk0 = sTk1[j0],     tk1v = sTk1[j1];
        red[8 + t * 3 + 0] = D0 * (tk0 + we0) + D1 * (tk1v + we1);  // fin_d partial
        red[8 + t * 3 + 1] = S0 * tk0 + S1 * tk1v;                  // fin_s partial
        red[8 + t * 3 + 2] = L0 * we0 + L1 * we1;                   // fin_l partial
    }

    #pragma unroll
    for (int s = 1; s < 64; s <<= 1) {
        #pragma unroll
        for (int k = 0; k < 14; ++k) red[k] += __shfl_xor(red[k], s, 64);
    }

    float Tb1v = Tb1[0];
    #pragma unroll
    for (int t = 0; t < 2; ++t) {
        float fd = red[8 + t * 3 + 0] + Tb1v + Tlb1[t];
        float fs = red[8 + t * 3 + 1] + Tb1v;
        float fl = red[8 + t * 3 + 2] + Tlb1[t];
        const float* hb = t ? h1b : h0b;
        float g0 = 1.f / (1.f + expf(-(red[t * 4 + 0] + hb[0])));
        float g1 = 1.f / (1.f + expf(-(red[t * 4 + 1] + hb[1])));
        float g2 = 1.f / (1.f + expf(-(red[t * 4 + 2] + hb[2])));
        float g3 = 1.f / (1.f + expf(-(red[t * 4 + 3] + hb[3])));
        float base = fd - g0 * fs - g1 * fl;
        size_t o = (size_t)t * BATCH * 128 + (size_t)b * 128;
        out[o + j0] = base - g2 * SLv[t][0] - g3 * LSv[t][0];
        out[o + j1] = base - g2 * SLv[t][1] - g3 * LSv[t][1];
    }
}

// ---------------- host ----------------
extern "C" void kernel_launch(void* const* d_in, const int* in_sizes, int n_in,
                              void* d_out, int out_size, void* d_ws, size_t ws_size,
                              hipStream_t stream)
{
    const int*   x    = (const int*)  d_in[0];
    const int*   dix  = (const int*)  d_in[1];
    const float* emb  = (const float*)d_in[2];
    const float* sW0  = (const float*)d_in[3];
    const float* sb0  = (const float*)d_in[4];
    const float* sW1  = (const float*)d_in[5];
    const float* sb1  = (const float*)d_in[6];
    const float* Dk0  = (const float*)d_in[7];
    const float* Db0  = (const float*)d_in[8];
    const float* DA0  = (const float*)d_in[9];
    const float* DB0  = (const float*)d_in[10];
    const float* Dlb0 = (const float*)d_in[11];
    const float* Tk0  = (const float*)d_in[12];
    const float* Tb0  = (const float*)d_in[13];
    const float* Tk1  = (const float*)d_in[14];
    const float* Tb1  = (const float*)d_in[15];
    const float* TA0  = (const float*)d_in[16];
    const float* TB0  = (const float*)d_in[17];
    const float* Tlb0 = (const float*)d_in[18];
    const float* TA1  = (const float*)d_in[19];
    const float* TB1  = (const float*)d_in[20];
    const float* Tlb1 = (const float*)d_in[21];
    const float* gW0  = (const float*)d_in[22];
    const float* gb0  = (const float*)d_in[23];
    const float* gW1  = (const float*)d_in[24];
    const float* gb1  = (const float*)d_in[25];
    const float* h0W  = (const float*)d_in[26];
    const float* h0b  = (const float*)d_in[27];
    const float* h1W  = (const float*)d_in[28];
    const float* h1b  = (const float*)d_in[29];

    char* ws = (char*)d_ws;
    size_t off = 0;
    auto alloc = [&](size_t bytes) -> void* {
        void* p = ws + off;
        off += (bytes + 255) & ~(size_t)255;
        return p;
    };
    unsigned short* W1t   = (unsigned short*)alloc((size_t)2048 * 2048 * 2);
    unsigned short* W2st  = (unsigned short*)alloc((size_t)512 * 1024 * 2);
    unsigned short* W2gt  = (unsigned short*)alloc((size_t)512 * 1024 * 2);
    unsigned short* Dk0t  = (unsigned short*)alloc((size_t)256 * 512 * 2);
    unsigned short* Tcat  = (unsigned short*)alloc((size_t)160 * 256 * 2);
    float*          b1cat = (float*)alloc(2048 * 4);
    float*          tb0c  = (float*)alloc(160 * 4);
    char* regA = (char*)alloc((size_t)BATCH * 2048 * 2);   // Xemb, later Yd/Ys/Yl
    char* regB = (char*)alloc((size_t)BATCH * 2048 * 2);   // H, later SHARE/LORA/DDNN
    unsigned short* Xdnn  = (unsigned short*)alloc((size_t)BATCH * 512 * 2);
    unsigned short* Hyper = (unsigned short*)alloc((size_t)BATCH * 512 * 2);

    unsigned short* Xemb = (unsigned short*)regA;
    float* Yd = (float*)regA;
    float* Ys = Yd + (size_t)BATCH * 160;
    float* Yl = Ys + (size_t)BATCH * 160;
    unsigned short* Hbuf  = (unsigned short*)regB;
    unsigned short* SHARE = (unsigned short*)regB;
    unsigned short* LORA  = SHARE + (size_t)BATCH * 256;
    unsigned short* DDNN  = LORA  + (size_t)BATCH * 256;

    dim3 tb(32, 8);
    // weight prep (bf16, transposed N x K)
    k_transpose_cvt<<<dim3(32, 64), tb, 0, stream>>>(sW0, 2048, 1024, W1t, 0,    2048);
    k_transpose_cvt<<<dim3(32, 64), tb, 0, stream>>>(gW0, 2048, 1024, W1t, 1024, 2048);
    k_transpose_cvt<<<dim3(16, 32), tb, 0, stream>>>(sW1, 1024, 512, W2st, 0, 1024);
    k_transpose_cvt<<<dim3(16, 32), tb, 0, stream>>>(gW1, 1024, 512, W2gt, 0, 1024);
    k_transpose_cvt<<<dim3(8, 16),  tb, 0, stream>>>(Dk0, 512, 256, Dk0t, 0, 512);
    k_transpose_cvt<<<dim3(4, 8),   tb, 0, stream>>>(Tk0, 256, 128, Tcat, 0,   256);
    k_transpose_cvt<<<dim3(1, 8),   tb, 0, stream>>>(TA0,           256, 16, Tcat, 128, 256);
    k_transpose_cvt<<<dim3(1, 8),   tb, 0, stream>>>(TA0 + 256*16,  256, 16, Tcat, 144, 256);
    k_copyf<<<4, 256, 0, stream>>>(sb0, b1cat, 1024);
    k_copyf<<<4, 256, 0, stream>>>(gb0, b1cat + 1024, 1024);
    k_copyf<<<1, 256, 0, stream>>>(Tb0, tb0c, 128);
    k_zerof<<<1, 256, 0, stream>>>(tb0c + 128, 32);

    // gather
    k_gather<<<32768, 256, 0, stream>>>(x, emb, Xemb);
    // GEMM1: x_emb @ [sW0|gW0], relu -> H (B,2048) bf16
    k_gemm<1, 1><<<dim3(16, 128), 256, 0, stream>>>(Xemb, 2048, W1t, b1cat, Hbuf, 2048, 2048, 2048);
    // GEMM2a/b: H halves -> x_dnn, hyper (B,512) bf16
    k_gemm<1, 1><<<dim3(4, 128), 256, 0, stream>>>(Hbuf,        2048, W2st, sb1, Xdnn,  512, 512, 1024);
    k_gemm<1, 1><<<dim3(4, 128), 256, 0, stream>>>(Hbuf + 1024, 2048, W2gt, gb1, Hyper, 512, 512, 1024);
    // GEMM3: share = x_dnn @ Dk0 + Db0 (pre-act) bf16
    k_gemm<0, 1><<<dim3(2, 128), 256, 0, stream>>>(Xdnn, 512, Dk0t, Db0, SHARE, 256, 256, 512);
    // domain LoRA + ddnn
    k_dlora<<<BATCH / 4, 256, 0, stream>>>(Xdnn, dix, DA0, DB0, Dlb0, SHARE, LORA, DDNN);
    // stage i=0: three streams @ [Tk0|TA0[0]|TA0[1]] -> Y (B,160) f32
    k_gemm<0, 0><<<dim3(2, 128), 256, 0, stream>>>(DDNN,  256, Tcat, tb0c, Yd, 160, 160, 256);
    k_gemm<0, 0><<<dim3(2, 128), 256, 0, stream>>>(SHARE, 256, Tcat, tb0c, Ys, 160, 160, 256);
    k_gemm<0, 0><<<dim3(2, 128), 256, 0, stream>>>(LORA,  256, Tcat, tb0c, Yl, 160, 160, 256);
    // fused tail
    k_tail<<<BATCH / 4, 256, 0, stream>>>(Yd, Ys, Yl, Hyper, TB0, Tlb0, Tk1, Tb1,
                                          TA1, TB1, Tlb1, h0W, h0b, h1W, h1b, (float*)d_out);
}

// Round 2
// 485.628 us; speedup vs baseline: 1.1931x; 1.1931x over previous
//
#include <hip/hip_runtime.h>
#include <hip/hip_bf16.h>

#define BATCH 16384

typedef __attribute__((ext_vector_type(4))) float f32x4;
typedef __attribute__((ext_vector_type(8))) short bf16x8;

__device__ inline float b2f(unsigned short u) {
    union { unsigned u; float f; } c; c.u = ((unsigned)u) << 16; return c.f;
}
__device__ inline unsigned short f2b(float f) {
    __hip_bfloat16 h = __float2bfloat16(f);
    return *(unsigned short*)&h;
}

#define GLL16(g, l)                                                            \
    __builtin_amdgcn_global_load_lds(                                          \
        (const __attribute__((address_space(1))) void*)(g),                    \
        (__attribute__((address_space(3))) void*)(l), 16, 0, 0)

// ---------------- weight prep: f32 (K x N) -> bf16 transposed (N x K) ----------------
__global__ void k_transpose_cvt(const float* __restrict__ src, int K, int N,
                                unsigned short* __restrict__ dst, int dst_off, int dst_ld)
{
    __shared__ float t[32][33];
    int k0 = blockIdx.y * 32, n0 = blockIdx.x * 32;
    int tx = threadIdx.x, ty = threadIdx.y; // 32 x 8
    #pragma unroll
    for (int s = 0; s < 32; s += 8) {
        int k = k0 + ty + s, n = n0 + tx;
        t[ty + s][tx] = (k < K && n < N) ? src[(size_t)k * N + n] : 0.f;
    }
    __syncthreads();
    #pragma unroll
    for (int s = 0; s < 32; s += 8) {
        int n = n0 + ty + s, k = k0 + tx;
        if (n < N && k < K)
            dst[(size_t)(dst_off + n) * dst_ld + k] = f2b(t[tx][ty + s]);
    }
}

__global__ void k_copyf(const float* __restrict__ src, float* __restrict__ dst, int n) {
    int i = blockIdx.x * 256 + threadIdx.x;
    if (i < n) dst[i] = src[i];
}
__global__ void k_zerof(float* __restrict__ dst, int n) {
    int i = blockIdx.x * 256 + threadIdx.x;
    if (i < n) dst[i] = 0.f;
}

// ---------------- embedding gather -> bf16 x_emb (B, 2048) ----------------
__global__ __launch_bounds__(256) void k_gather(const int* __restrict__ x,
                                                const float* __restrict__ emb,
                                                unsigned short* __restrict__ Xemb)
{
    int i = blockIdx.x * 256 + threadIdx.x;   // group of 4 elements
    int b  = i >> 9;                          // 512 groups per row of 2048
    int j4 = (i & 511) << 2;
    int f  = j4 >> 6;
    int l  = j4 & 63;
    int idx = x[b * 32 + f];
    float4 v = *(const float4*)(emb + (size_t)idx * 64 + l);
    ushort4 o;
    o.x = f2b(v.x); o.y = f2b(v.y); o.z = f2b(v.z); o.w = f2b(v.w);
    *(ushort4*)(Xemb + (size_t)b * 2048 + j4) = o;
}

// ---------------- bf16 MFMA GEMM (m97 structure): global_load_lds staging ----------------
// C(MxN) = A(MxK) * Bt(NxK)^T + bias, opt relu. M multiple of 128 (grid.y*128),
// K multiple of 32. N masked (B-rows clamped on load, columns masked on store).
// LDS linear [128][32] bf16 per operand; both-sides XOR chunk swizzle:
//   LDS (row R, chunk pos p) holds global chunk p ^ ((R>>1)&3)  [16B chunks]
template<int RELU, int OUTBF16>
__global__ __launch_bounds__(256) void k_gemm(
    const unsigned short* __restrict__ A, int lda,
    const unsigned short* __restrict__ Bt,         // N x K row-major, ldb = K
    const float* __restrict__ bias,
    void* __restrict__ C, int ldc,
    int N, int K)
{
    __shared__ __align__(16) unsigned short As[128 * 32];
    __shared__ __align__(16) unsigned short Bs[128 * 32];
    const int tid  = threadIdx.x;
    const int lane = tid & 63;
    const int w    = tid >> 6;
    const int wr   = w >> 1, wc = w & 1;
    const int row0 = blockIdx.y * 128;
    const int col0 = blockIdx.x * 128;
    const int frow = lane & 15;
    const int kg   = lane >> 4;                    // k-group 0..3
    const int sw   = kg ^ ((frow >> 1) & 3);       // read-side swizzled chunk

    // staging: wave w stages LDS chunks (w*2), (w*2+1) => rows w*32 .. w*32+31.
    // lane covers row +lane>>2, LDS chunk pos lane&3; source chunk pre-swizzled.
    const int srow = w * 32 + (lane >> 2);
    const int csw  = (lane & 3) ^ ((lane >> 3) & 3);
    const int br0  = min(col0 + srow, N - 1);
    const int br1  = min(col0 + srow + 16, N - 1);

    const unsigned short* a0 = A  + (size_t)(row0 + srow) * lda      + csw * 8;
    const unsigned short* a1 = A  + (size_t)(row0 + srow + 16) * lda + csw * 8;
    const unsigned short* b0 = Bt + (size_t)br0 * K + csw * 8;
    const unsigned short* b1 = Bt + (size_t)br1 * K + csw * 8;
    unsigned short* lA0 = As + (w * 2 + 0) * 512;
    unsigned short* lA1 = As + (w * 2 + 1) * 512;
    unsigned short* lB0 = Bs + (w * 2 + 0) * 512;
    unsigned short* lB1 = Bs + (w * 2 + 1) * 512;

    f32x4 acc[4][4] = {};

    for (int bk = 0; bk < K; bk += 32) {
        __syncthreads();                 // previous tile fully consumed
        GLL16(a0 + bk, lA0);
        GLL16(a1 + bk, lA1);
        GLL16(b0 + bk, lB0);
        GLL16(b1 + bk, lB1);
        __syncthreads();                 // drains vmcnt -> tile visible
        bf16x8 af[4], bfr[4];
        #pragma unroll
        for (int m = 0; m < 4; ++m)
            af[m] = *(const bf16x8*)&As[(wr * 64 + m * 16 + frow) * 32 + sw * 8];
        #pragma unroll
        for (int n = 0; n < 4; ++n)
            bfr[n] = *(const bf16x8*)&Bs[(wc * 64 + n * 16 + frow) * 32 + sw * 8];
        #pragma unroll
        for (int m = 0; m < 4; ++m)
            #pragma unroll
            for (int n = 0; n < 4; ++n)
                acc[m][n] = __builtin_amdgcn_mfma_f32_16x16x32_bf16(af[m], bfr[n], acc[m][n], 0, 0, 0);
    }

    // epilogue: C/D layout col=lane&15, row=(lane>>4)*4+reg   [m89-verified]
    #pragma unroll
    for (int n = 0; n < 4; ++n) {
        int gcol = col0 + wc * 64 + n * 16 + frow;
        if (gcol >= N) continue;
        float bv = bias[gcol];
        #pragma unroll
        for (int m = 0; m < 4; ++m) {
            int gr = row0 + wr * 64 + m * 16 + kg * 4;
            #pragma unroll
            for (int r = 0; r < 4; ++r) {
                float v = acc[m][n][r] + bv;
                if (RELU) v = fmaxf(v, 0.f);
                size_t idx = (size_t)(gr + r) * ldc + gcol;
                if (OUTBF16) ((unsigned short*)C)[idx] = f2b(v);
                else         ((float*)C)[idx] = v;
            }
        }
    }
}

// ---------------- per-sample domain LoRA: lora = (x@DA0[d])@DB0[d]+Dlb0[d]; ddnn=relu(share+lora) ----------------
__global__ __launch_bounds__(256) void k_dlora(
    const unsigned short* __restrict__ Xdnn, const int* __restrict__ d,
    const float* __restrict__ DA0, const float* __restrict__ DB0, const float* __restrict__ Dlb0,
    const unsigned short* __restrict__ SHARE,
    unsigned short* __restrict__ LORA, unsigned short* __restrict__ DDNN)
{
    int w = threadIdx.x >> 6, lane = threadIdx.x & 63;
    int b = blockIdx.x * 4 + w;
    int dom = d[b];
    uint4 raw = *(const uint4*)(Xdnn + (size_t)b * 512 + lane * 8);
    const unsigned short* pr = (const unsigned short*)&raw;
    float xv[8];
    #pragma unroll
    for (int j = 0; j < 8; ++j) xv[j] = b2f(pr[j]);

    const float* Ap = DA0 + ((size_t)dom * 512 + lane * 8) * 16;
    float v[16];
    #pragma unroll
    for (int r = 0; r < 16; ++r) v[r] = 0.f;
    #pragma unroll
    for (int j = 0; j < 8; ++j) {
        float xj = xv[j];
        #pragma unroll
        for (int r = 0; r < 16; ++r) v[r] += xj * Ap[j * 16 + r];
    }
    #pragma unroll
    for (int s = 1; s < 64; s <<= 1) {
        #pragma unroll
        for (int r = 0; r < 16; ++r) v[r] += __shfl_xor(v[r], s, 64);
    }
    const float* Bp  = DB0 + (size_t)dom * 16 * 256;
    const float* lbp = Dlb0 + (size_t)dom * 256;
    #pragma unroll
    for (int c = 0; c < 4; ++c) {
        int o = lane + c * 64;
        float a = lbp[o];
        #pragma unroll
        for (int r = 0; r < 16; ++r) a += v[r] * Bp[r * 256 + o];
        float sh = b2f(SHARE[(size_t)b * 256 + o]);
        LORA[(size_t)b * 256 + o] = f2b(a);
        DDNN[(size_t)b * 256 + o] = f2b(fmaxf(sh + a, 0.f));
    }
}

// ---------------- fused tail: task-0 LoRA expansion, i=1 collapse, gates, output ----------------
__global__ __launch_bounds__(256) void k_tail(
    const float* __restrict__ Yd, const float* __restrict__ Ys, const float* __restrict__ Yl,
    const unsigned short* __restrict__ Hyper,
    const float* __restrict__ TB0, const float* __restrict__ Tlb0,
    const float* __restrict__ Tk1, const float* __restrict__ Tb1,
    const float* __restrict__ TA1, const float* __restrict__ TB1, const float* __restrict__ Tlb1,
    const float* __restrict__ h0W, const float* __restrict__ h0b,
    const float* __restrict__ h1W, const float* __restrict__ h1b,
    float* __restrict__ out)
{
    __shared__ float sTB0[2][16][128];
    __shared__ float sTlb0[2][128];
    __shared__ float sTk1[128];
    __shared__ float sWeff[2][128];
    __shared__ float sY[4][3][160];
    const int tid = threadIdx.x;

    for (int i = tid; i < 4096; i += 256) ((float*)sTB0)[i] = TB0[i];
    if (tid < 256) ((float*)sTlb0)[tid] = Tlb0[tid];
    if (tid < 128) sTk1[tid] = Tk1[tid];
    {
        int t = tid >> 7, j = tid & 127;
        float a = 0.f;
        #pragma unroll
        for (int r = 0; r < 16; ++r) a += TA1[((size_t)t * 128 + j) * 16 + r] * TB1[t * 16 + r];
        sWeff[t][j] = a;  // TA1[t] . TB1[t]  (collapsed rank-16 path)
    }
    const float* Yp[3] = {Yd, Ys, Yl};
    int b0 = blockIdx.x * 4;
    for (int i = tid; i < 4 * 3 * 160; i += 256) {
        int s = i / 480, rem = i % 480, st = rem / 160, idx = rem % 160;
        sY[s][st][idx] = Yp[st][(size_t)(b0 + s) * 160 + idx];
    }
    __syncthreads();

    int w = tid >> 6, lane = tid & 63;
    int b = b0 + w;
    const float* yd = sY[w][0];
    const float* ys = sY[w][1];
    const float* yl = sY[w][2];
    int j0 = lane, j1 = lane + 64;

    // gate partials: hyper[b] . h{0,1}W
    uint4 hraw = *(const uint4*)(Hyper + (size_t)b * 512 + lane * 8);
    const unsigned short* hp = (const unsigned short*)&hraw;
    float hv[8];
    #pragma unroll
    for (int j = 0; j < 8; ++j) hv[j] = b2f(hp[j]);

    float red[14];
    #pragma unroll
    for (int k = 0; k < 14; ++k) red[k] = 0.f;
    #pragma unroll
    for (int j = 0; j < 8; ++j) {
        float4 w0 = *(const float4*)(h0W + (size_t)(lane * 8 + j) * 4);
        float4 w1 = *(const float4*)(h1W + (size_t)(lane * 8 + j) * 4);
        red[0] += hv[j] * w0.x; red[1] += hv[j] * w0.y; red[2] += hv[j] * w0.z; red[3] += hv[j] * w0.w;
        red[4] += hv[j] * w1.x; red[5] += hv[j] * w1.y; red[6] += hv[j] * w1.z; red[7] += hv[j] * w1.w;
    }

    float SLv[2][2], LSv[2][2];
    #pragma unroll
    for (int t = 0; t < 2; ++t) {
        float lb0 = sTlb0[t][j0], lb1 = sTlb0[t][j1];
        float dl0 = lb0, dl1 = lb1, sl0 = lb0, sl1 = lb1, ll0 = lb0, ll1 = lb1;
        #pragma unroll
        for (int r = 0; r < 16; ++r) {
            float w0v = sTB0[t][r][j0], w1v = sTB0[t][r][j1];
            float ud = yd[128 + t * 16 + r];
            float us = ys[128 + t * 16 + r];
            float ul = yl[128 + t * 16 + r];
            dl0 += ud * w0v; dl1 += ud * w1v;
            sl0 += us * w0v; sl1 += us * w1v;
            ll0 += ul * w0v; ll1 += ul * w1v;
        }
        float D0 = yd[j0] + dl0, D1 = yd[j1] + dl1;   // ds + dl
        float S0 = ys[j0],       S1 = ys[j1];         // ss
        float L0 = ll0,          L1 = ll1;            // ll
        float sl_0 = sl0, sl_1 = sl1;                 // sl
        float ls_0 = yl[j0], ls_1 = yl[j1];           // ls
        if (t == 0) {  // relu fires only at (i=0, t=0)
            D0 = fmaxf(D0, 0.f); D1 = fmaxf(D1, 0.f);
            S0 = fmaxf(S0, 0.f); S1 = fmaxf(S1, 0.f);
            L0 = fmaxf(L0, 0.f); L1 = fmaxf(L1, 0.f);
            sl_0 = fmaxf(sl_0, 0.f); sl_1 = fmaxf(sl_1, 0.f);
            ls_0 = fmaxf(ls_0, 0.f); ls_1 = fmaxf(ls_1, 0.f);
        }
        SLv[t][0] = sl_0; SLv[t][1] = sl_1;
        LSv[t][0] = ls_0; LSv[t][1] = ls_1;
        float we0 = sWeff[t][j0], we1 = sWeff[t][j1];
        float tk0 = sTk1[j0],     tk1v = sTk1[j1];
        red[8 + t * 3 + 0] = D0 * (tk0 + we0) + D1 * (tk1v + we1);  // fin_d partial
        red[8 + t * 3 + 1] = S0 * tk0 + S1 * tk1v;                  // fin_s partial
        red[8 + t * 3 + 2] = L0 * we0 + L1 * we1;                   // fin_l partial
    }

    #pragma unroll
    for (int s = 1; s < 64; s <<= 1) {
        #pragma unroll
        for (int k = 0; k < 14; ++k) red[k] += __shfl_xor(red[k], s, 64);
    }

    float Tb1v = Tb1[0];
    #pragma unroll
    for (int t = 0; t < 2; ++t) {
        float fd = red[8 + t * 3 + 0] + Tb1v + Tlb1[t];
        float fs = red[8 + t * 3 + 1] + Tb1v;
        float fl = red[8 + t * 3 + 2] + Tlb1[t];
        const float* hb = t ? h1b : h0b;
        float g0 = 1.f / (1.f + expf(-(red[t * 4 + 0] + hb[0])));
        float g1 = 1.f / (1.f + expf(-(red[t * 4 + 1] + hb[1])));
        float g2 = 1.f / (1.f + expf(-(red[t * 4 + 2] + hb[2])));
        float g3 = 1.f / (1.f + expf(-(red[t * 4 + 3] + hb[3])));
        float base = fd - g0 * fs - g1 * fl;
        size_t o = (size_t)t * BATCH * 128 + (size_t)b * 128;
        out[o + j0] = base - g2 * SLv[t][0] - g3 * LSv[t][0];
        out[o + j1] = base - g2 * SLv[t][1] - g3 * LSv[t][1];
    }
}

// ---------------- host ----------------
extern "C" void kernel_launch(void* const* d_in, const int* in_sizes, int n_in,
                              void* d_out, int out_size, void* d_ws, size_t ws_size,
                              hipStream_t stream)
{
    const int*   x    = (const int*)  d_in[0];
    const int*   dix  = (const int*)  d_in[1];
    const float* emb  = (const float*)d_in[2];
    const float* sW0  = (const float*)d_in[3];
    const float* sb0  = (const float*)d_in[4];
    const float* sW1  = (const float*)d_in[5];
    const float* sb1  = (const float*)d_in[6];
    const float* Dk0  = (const float*)d_in[7];
    const float* Db0  = (const float*)d_in[8];
    const float* DA0  = (const float*)d_in[9];
    const float* DB0  = (const float*)d_in[10];
    const float* Dlb0 = (const float*)d_in[11];
    const float* Tk0  = (const float*)d_in[12];
    const float* Tb0  = (const float*)d_in[13];
    const float* Tk1  = (const float*)d_in[14];
    const float* Tb1  = (const float*)d_in[15];
    const float* TA0  = (const float*)d_in[16];
    const float* TB0  = (const float*)d_in[17];
    const float* Tlb0 = (const float*)d_in[18];
    const float* TA1  = (const float*)d_in[19];
    const float* TB1  = (const float*)d_in[20];
    const float* Tlb1 = (const float*)d_in[21];
    const float* gW0  = (const float*)d_in[22];
    const float* gb0  = (const float*)d_in[23];
    const float* gW1  = (const float*)d_in[24];
    const float* gb1  = (const float*)d_in[25];
    const float* h0W  = (const float*)d_in[26];
    const float* h0b  = (const float*)d_in[27];
    const float* h1W  = (const float*)d_in[28];
    const float* h1b  = (const float*)d_in[29];

    char* ws = (char*)d_ws;
    size_t off = 0;
    auto alloc = [&](size_t bytes) -> void* {
        void* p = ws + off;
        off += (bytes + 255) & ~(size_t)255;
        return p;
    };
    unsigned short* W1t   = (unsigned short*)alloc((size_t)2048 * 2048 * 2);
    unsigned short* W2st  = (unsigned short*)alloc((size_t)512 * 1024 * 2);
    unsigned short* W2gt  = (unsigned short*)alloc((size_t)512 * 1024 * 2);
    unsigned short* Dk0t  = (unsigned short*)alloc((size_t)256 * 512 * 2);
    unsigned short* Tcat  = (unsigned short*)alloc((size_t)160 * 256 * 2);
    float*          b1cat = (float*)alloc(2048 * 4);
    float*          tb0c  = (float*)alloc(160 * 4);
    char* regA = (char*)alloc((size_t)BATCH * 2048 * 2);   // Xemb, later Ys/Yl/Yd
    char* regB = (char*)alloc((size_t)BATCH * 2048 * 2);   // H, later SHARE/LORA/DDNN
    unsigned short* Xdnn  = (unsigned short*)alloc((size_t)BATCH * 512 * 2);
    unsigned short* Hyper = (unsigned short*)alloc((size_t)BATCH * 512 * 2);

    unsigned short* Xemb = (unsigned short*)regA;
    float* Ybase = (float*)regA;
    float* Ys = Ybase;                              // stream order: SHARE, LORA, DDNN
    float* Yl = Ybase + (size_t)BATCH * 160;
    float* Yd = Ybase + (size_t)2 * BATCH * 160;
    unsigned short* Hbuf  = (unsigned short*)regB;
    unsigned short* SHARE = (unsigned short*)regB;
    unsigned short* LORA  = SHARE + (size_t)BATCH * 256;
    unsigned short* DDNN  = LORA  + (size_t)BATCH * 256;

    dim3 tb(32, 8);
    // weight prep (bf16, transposed N x K)
    k_transpose_cvt<<<dim3(32, 64), tb, 0, stream>>>(sW0, 2048, 1024, W1t, 0,    2048);
    k_transpose_cvt<<<dim3(32, 64), tb, 0, stream>>>(gW0, 2048, 1024, W1t, 1024, 2048);
    k_transpose_cvt<<<dim3(16, 32), tb, 0, stream>>>(sW1, 1024, 512, W2st, 0, 1024);
    k_transpose_cvt<<<dim3(16, 32), tb, 0, stream>>>(gW1, 1024, 512, W2gt, 0, 1024);
    k_transpose_cvt<<<dim3(8, 16),  tb, 0, stream>>>(Dk0, 512, 256, Dk0t, 0, 512);
    k_transpose_cvt<<<dim3(4, 8),   tb, 0, stream>>>(Tk0, 256, 128, Tcat, 0,   256);
    k_transpose_cvt<<<dim3(1, 8),   tb, 0, stream>>>(TA0,           256, 16, Tcat, 128, 256);
    k_transpose_cvt<<<dim3(1, 8),   tb, 0, stream>>>(TA0 + 256*16,  256, 16, Tcat, 144, 256);
    k_copyf<<<4, 256, 0, stream>>>(sb0, b1cat, 1024);
    k_copyf<<<4, 256, 0, stream>>>(gb0, b1cat + 1024, 1024);
    k_copyf<<<1, 256, 0, stream>>>(Tb0, tb0c, 128);
    k_zerof<<<1, 256, 0, stream>>>(tb0c + 128, 32);

    // gather
    k_gather<<<32768, 256, 0, stream>>>(x, emb, Xemb);
    // GEMM1: x_emb @ [sW0|gW0], relu -> H (B,2048) bf16
    k_gemm<1, 1><<<dim3(16, 128), 256, 0, stream>>>(Xemb, 2048, W1t, b1cat, Hbuf, 2048, 2048, 2048);
    // GEMM2a/b: H halves -> x_dnn, hyper (B,512) bf16
    k_gemm<1, 1><<<dim3(4, 128), 256, 0, stream>>>(Hbuf,        2048, W2st, sb1, Xdnn,  512, 512, 1024);
    k_gemm<1, 1><<<dim3(4, 128), 256, 0, stream>>>(Hbuf + 1024, 2048, W2gt, gb1, Hyper, 512, 512, 1024);
    // GEMM3: share = x_dnn @ Dk0 + Db0 (pre-act) bf16
    k_gemm<0, 1><<<dim3(2, 128), 256, 0, stream>>>(Xdnn, 512, Dk0t, Db0, SHARE, 256, 256, 512);
    // domain LoRA + ddnn
    k_dlora<<<BATCH / 4, 256, 0, stream>>>(Xdnn, dix, DA0, DB0, Dlb0, SHARE, LORA, DDNN);
    // stage i=0: ONE fused GEMM over the 3 contiguous streams (SHARE,LORA,DDNN) @ [Tk0|TA0[0]|TA0[1]]
    k_gemm<0, 0><<<dim3(2, 384), 256, 0, stream>>>(SHARE, 256, Tcat, tb0c, Ybase, 160, 160, 256);
    // fused tail
    k_tail<<<BATCH / 4, 256, 0, stream>>>(Yd, Ys, Yl, Hyper, TB0, Tlb0, Tk1, Tb1,
                                          TA1, TB1, Tlb1, h0W, h0b, h1W, h1b, (float*)d_out);
}

// Round 3
// 412.893 us; speedup vs baseline: 1.4033x; 1.1762x over previous
//
#include <hip/hip_runtime.h>
#include <hip/hip_bf16.h>

#define BATCH 16384

typedef __attribute__((ext_vector_type(4))) float f32x4;
typedef __attribute__((ext_vector_type(8))) short bf16x8;

__device__ inline float b2f(unsigned short u) {
    union { unsigned u; float f; } c; c.u = ((unsigned)u) << 16; return c.f;
}
__device__ inline unsigned short f2b(float f) {
    __hip_bfloat16 h = __float2bfloat16(f);
    return *(unsigned short*)&h;
}

#define GLL16(g, l)                                                            \
    __builtin_amdgcn_global_load_lds(                                          \
        (const __attribute__((address_space(1))) void*)(g),                    \
        (__attribute__((address_space(3))) void*)(l), 16, 0, 0)

// ---------------- weight prep: f32 (K x N) -> bf16 transposed (N x K) ----------------
__global__ void k_transpose_cvt(const float* __restrict__ src, int K, int N,
                                unsigned short* __restrict__ dst, int dst_off, int dst_ld)
{
    __shared__ float t[32][33];
    int k0 = blockIdx.y * 32, n0 = blockIdx.x * 32;
    int tx = threadIdx.x, ty = threadIdx.y; // 32 x 8
    #pragma unroll
    for (int s = 0; s < 32; s += 8) {
        int k = k0 + ty + s, n = n0 + tx;
        t[ty + s][tx] = (k < K && n < N) ? src[(size_t)k * N + n] : 0.f;
    }
    __syncthreads();
    #pragma unroll
    for (int s = 0; s < 32; s += 8) {
        int n = n0 + ty + s, k = k0 + tx;
        if (n < N && k < K)
            dst[(size_t)(dst_off + n) * dst_ld + k] = f2b(t[tx][ty + s]);
    }
}

__global__ void k_copyf(const float* __restrict__ src, float* __restrict__ dst, int n) {
    int i = blockIdx.x * 256 + threadIdx.x;
    if (i < n) dst[i] = src[i];
}
__global__ void k_zerof(float* __restrict__ dst, int n) {
    int i = blockIdx.x * 256 + threadIdx.x;
    if (i < n) dst[i] = 0.f;
}

// ---------------- embedding gather -> bf16 x_emb (B, 2048) ----------------
__global__ __launch_bounds__(256) void k_gather(const int* __restrict__ x,
                                                const float* __restrict__ emb,
                                                unsigned short* __restrict__ Xemb)
{
    int i = blockIdx.x * 256 + threadIdx.x;   // group of 4 elements
    int b  = i >> 9;                          // 512 groups per row of 2048
    int j4 = (i & 511) << 2;
    int f  = j4 >> 6;
    int l  = j4 & 63;
    int idx = x[b * 32 + f];
    float4 v = *(const float4*)(emb + (size_t)idx * 64 + l);
    ushort4 o;
    o.x = f2b(v.x); o.y = f2b(v.y); o.z = f2b(v.z); o.w = f2b(v.w);
    *(ushort4*)(Xemb + (size_t)b * 2048 + j4) = o;
}

// ================= 256x256 8-phase MFMA GEMM (T2+T3+T4+T5) ====================
// C(MxN) = A(MxK) * Bt(NxK)^T + bias, opt relu. Tile 256x256, BK-slab=32,
// 512 threads (8 waves, 2Mx4N), LDS ring of 4 slabs x 32KB (A+B interleaved,
// row stride 128B, XOR chunk swizzle p = l ^ (row&7), both-sides).
// Schedule per iteration (4 slabs, 8 phases): phase(j,mh) reads slab j
// (slot j), stages half (mh) of slab k+3+j into slot (3+j)&3; vmcnt(4) only
// at ph3/ph7; raw barriers; setprio around 16-MFMA cluster.
// blockIdx.z groups independent GEMMs (A/B/bias/C offset by z strides).
template<int RELU, int OUTBF16>
__global__ __launch_bounds__(512, 2) void k_gemm256(
    const unsigned short* __restrict__ A, int lda, long Az,
    const unsigned short* __restrict__ Bt, int K, long Bz,
    const float* __restrict__ bias, int biasz,
    void* __restrict__ C, int ldc, long Cz,
    int N)
{
    extern __shared__ char smem_raw[];
    const int NS = K >> 5;            // 32-wide K slabs
    const int NI = NS >> 2;           // iterations (4 slabs each)
    const int tid  = threadIdx.x;
    const int lane = tid & 63;
    const int w    = tid >> 6;
    const int wr   = w >> 2, wc = w & 3;
    const int frow = lane & 15, kg = lane >> 4;
    const int z = blockIdx.z;
    A    += (size_t)z * Az;
    Bt   += (size_t)z * Bz;
    bias += (size_t)z * biasz;

    // XCD-aware bijective swizzle (nwg divisible by 8 for all our launches)
    const int gx  = gridDim.x;
    const int nwg = gx * gridDim.y;
    const int lin = blockIdx.y * gx + blockIdx.x;
    const int qq  = nwg >> 3;
    const int swz = (lin & 7) * qq + (lin >> 3);
    const int bx = swz % gx, by = swz / gx;
    const int row0 = by * 256, col0 = bx * 256;

    // staging sources: 4 rounds of 8KB (idx = h*2+r2), per-lane pre-swizzled
    const int lch = (tid & 7) ^ ((tid >> 3) & 7);   // logical chunk this lane feeds
    const unsigned short* gsrc[4];
    int dOff[4];
    #pragma unroll
    for (int h = 0; h < 2; ++h)
        #pragma unroll
        for (int r2 = 0; r2 < 2; ++r2) {
            int rr = h * 128 + r2 * 64 + (tid >> 3);   // row in slab
            const unsigned short* p;
            if (lch < 4) p = A  + (size_t)(row0 + rr) * lda + lch * 8;
            else         p = Bt + (size_t)min(col0 + rr, N - 1) * K + (lch - 4) * 8;
            gsrc[h * 2 + r2] = p;
            dOff[h * 2 + r2] = h * 16384 + r2 * 8192 + w * 1024;   // wave-uniform LDS base
        }

    // fragment read offsets (bytes) within a slab; swizzled physical chunks
    const int pA = kg ^ (frow & 7);
    const int pB = (4 + kg) ^ (frow & 7);
    int aOff[8], bOff[4];
    #pragma unroll
    for (int m = 0; m < 8; ++m) aOff[m] = (wr * 128 + m * 16 + frow) * 128 + pA * 16;
    #pragma unroll
    for (int n = 0; n < 4; ++n) bOff[n] = (wc * 64 + n * 16 + frow) * 128 + pB * 16;

#define STAGE(sIdx, hh) do {                                                     \
        int rp_ = (sIdx) & 3;                                                    \
        int s_  = min((int)(sIdx), NS - 1);                                      \
        GLL16(gsrc[(hh)*2+0] + s_ * 32, smem_raw + rp_ * 32768 + dOff[(hh)*2+0]);\
        GLL16(gsrc[(hh)*2+1] + s_ * 32, smem_raw + rp_ * 32768 + dOff[(hh)*2+1]);\
    } while (0)

    f32x4 acc[8][4] = {};
    bf16x8 afr[4], bfr[4];

    // prologue: slabs 0,1,2 -> slots 0,1,2 ; wait slabs 0,1
    STAGE(0, 0); STAGE(0, 1); STAGE(1, 0); STAGE(1, 1); STAGE(2, 0); STAGE(2, 1);
    asm volatile("s_waitcnt vmcnt(4)" ::: "memory");
    __builtin_amdgcn_s_barrier();

    for (int it = 0; it < NI; ++it) {
        int k = it * 4;
        #pragma unroll
        for (int ph = 0; ph < 8; ++ph) {
            const int j = ph >> 1, mh = ph & 1;
            const char* sb = smem_raw + ((k + j) & 3) * 32768;
            if (mh == 0) {
                #pragma unroll
                for (int n = 0; n < 4; ++n)
                    bfr[n] = *(const bf16x8*)(sb + bOff[n]);
            }
            #pragma unroll
            for (int mi = 0; mi < 4; ++mi)
                afr[mi] = *(const bf16x8*)(sb + aOff[mh * 4 + mi]);
            if (mh == 0) STAGE(k + 3 + j, 0);
            else         STAGE(k + 3 + j, 1);
            if (ph == 3 || ph == 7)
                asm volatile("s_waitcnt vmcnt(4)" ::: "memory");
            __builtin_amdgcn_s_barrier();
            asm volatile("s_waitcnt lgkmcnt(0)" ::: "memory");
            __builtin_amdgcn_sched_barrier(0);
            __builtin_amdgcn_s_setprio(1);
            #pragma unroll
            for (int mi = 0; mi < 4; ++mi)
                #pragma unroll
                for (int n = 0; n < 4; ++n)
                    acc[mh * 4 + mi][n] = __builtin_amdgcn_mfma_f32_16x16x32_bf16(
                        afr[mi], bfr[n], acc[mh * 4 + mi][n], 0, 0, 0);
            __builtin_amdgcn_s_setprio(0);
            __builtin_amdgcn_s_barrier();
        }
    }
#undef STAGE

    // epilogue: C/D layout col=lane&15, row=(lane>>4)*4+reg
    #pragma unroll
    for (int n = 0; n < 4; ++n) {
        int gcol = col0 + wc * 64 + n * 16 + frow;
        if (gcol >= N) continue;
        float bv = bias[gcol];
        #pragma unroll
        for (int m = 0; m < 8; ++m) {
            int gr = row0 + wr * 128 + m * 16 + kg * 4;
            #pragma unroll
            for (int r = 0; r < 4; ++r) {
                float v = acc[m][n][r] + bv;
                if (RELU) v = fmaxf(v, 0.f);
                size_t idx = (size_t)(gr + r) * ldc + gcol;
                if (OUTBF16) ((unsigned short*)C + (size_t)z * Cz)[idx] = f2b(v);
                else         ((float*)C + (size_t)z * Cz)[idx] = v;
            }
        }
    }
}

// ---------------- 128x128 MFMA GEMM (m97 structure) for small GEMMs ----------------
template<int RELU, int OUTBF16>
__global__ __launch_bounds__(256) void k_gemm(
    const unsigned short* __restrict__ A, int lda,
    const unsigned short* __restrict__ Bt,         // N x K row-major, ldb = K
    const float* __restrict__ bias,
    void* __restrict__ C, int ldc,
    int N, int K)
{
    __shared__ __align__(16) unsigned short As[128 * 32];
    __shared__ __align__(16) unsigned short Bs[128 * 32];
    const int tid  = threadIdx.x;
    const int lane = tid & 63;
    const int w    = tid >> 6;
    const int wr   = w >> 1, wc = w & 1;
    const int row0 = blockIdx.y * 128;
    const int col0 = blockIdx.x * 128;
    const int frow = lane & 15;
    const int kg   = lane >> 4;
    const int sw   = kg ^ ((frow >> 1) & 3);

    const int srow = w * 32 + (lane >> 2);
    const int csw  = (lane & 3) ^ ((lane >> 3) & 3);
    const int br0  = min(col0 + srow, N - 1);
    const int br1  = min(col0 + srow + 16, N - 1);

    const unsigned short* a0 = A  + (size_t)(row0 + srow) * lda      + csw * 8;
    const unsigned short* a1 = A  + (size_t)(row0 + srow + 16) * lda + csw * 8;
    const unsigned short* b0 = Bt + (size_t)br0 * K + csw * 8;
    const unsigned short* b1 = Bt + (size_t)br1 * K + csw * 8;
    unsigned short* lA0 = As + (w * 2 + 0) * 512;
    unsigned short* lA1 = As + (w * 2 + 1) * 512;
    unsigned short* lB0 = Bs + (w * 2 + 0) * 512;
    unsigned short* lB1 = Bs + (w * 2 + 1) * 512;

    f32x4 acc[4][4] = {};

    for (int bk = 0; bk < K; bk += 32) {
        __syncthreads();
        GLL16(a0 + bk, lA0);
        GLL16(a1 + bk, lA1);
        GLL16(b0 + bk, lB0);
        GLL16(b1 + bk, lB1);
        __syncthreads();
        bf16x8 af[4], bfr[4];
        #pragma unroll
        for (int m = 0; m < 4; ++m)
            af[m] = *(const bf16x8*)&As[(wr * 64 + m * 16 + frow) * 32 + sw * 8];
        #pragma unroll
        for (int n = 0; n < 4; ++n)
            bfr[n] = *(const bf16x8*)&Bs[(wc * 64 + n * 16 + frow) * 32 + sw * 8];
        #pragma unroll
        for (int m = 0; m < 4; ++m)
            #pragma unroll
            for (int n = 0; n < 4; ++n)
                acc[m][n] = __builtin_amdgcn_mfma_f32_16x16x32_bf16(af[m], bfr[n], acc[m][n], 0, 0, 0);
    }

    #pragma unroll
    for (int n = 0; n < 4; ++n) {
        int gcol = col0 + wc * 64 + n * 16 + frow;
        if (gcol >= N) continue;
        float bv = bias[gcol];
        #pragma unroll
        for (int m = 0; m < 4; ++m) {
            int gr = row0 + wr * 64 + m * 16 + kg * 4;
            #pragma unroll
            for (int r = 0; r < 4; ++r) {
                float v = acc[m][n][r] + bv;
                if (RELU) v = fmaxf(v, 0.f);
                size_t idx = (size_t)(gr + r) * ldc + gcol;
                if (OUTBF16) ((unsigned short*)C)[idx] = f2b(v);
                else         ((float*)C)[idx] = v;
            }
        }
    }
}

// ---------------- per-sample domain LoRA ----------------
__global__ __launch_bounds__(256) void k_dlora(
    const unsigned short* __restrict__ Xdnn, const int* __restrict__ d,
    const float* __restrict__ DA0, const float* __restrict__ DB0, const float* __restrict__ Dlb0,
    const unsigned short* __restrict__ SHARE,
    unsigned short* __restrict__ LORA, unsigned short* __restrict__ DDNN)
{
    int w = threadIdx.x >> 6, lane = threadIdx.x & 63;
    int b = blockIdx.x * 4 + w;
    int dom = d[b];
    uint4 raw = *(const uint4*)(Xdnn + (size_t)b * 512 + lane * 8);
    const unsigned short* pr = (const unsigned short*)&raw;
    float xv[8];
    #pragma unroll
    for (int j = 0; j < 8; ++j) xv[j] = b2f(pr[j]);

    const float* Ap = DA0 + ((size_t)dom * 512 + lane * 8) * 16;
    float v[16];
    #pragma unroll
    for (int r = 0; r < 16; ++r) v[r] = 0.f;
    #pragma unroll
    for (int j = 0; j < 8; ++j) {
        float xj = xv[j];
        #pragma unroll
        for (int r = 0; r < 16; ++r) v[r] += xj * Ap[j * 16 + r];
    }
    #pragma unroll
    for (int s = 1; s < 64; s <<= 1) {
        #pragma unroll
        for (int r = 0; r < 16; ++r) v[r] += __shfl_xor(v[r], s, 64);
    }
    const float* Bp  = DB0 + (size_t)dom * 16 * 256;
    const float* lbp = Dlb0 + (size_t)dom * 256;
    #pragma unroll
    for (int c = 0; c < 4; ++c) {
        int o = lane + c * 64;
        float a = lbp[o];
        #pragma unroll
        for (int r = 0; r < 16; ++r) a += v[r] * Bp[r * 256 + o];
        float sh = b2f(SHARE[(size_t)b * 256 + o]);
        LORA[(size_t)b * 256 + o] = f2b(a);
        DDNN[(size_t)b * 256 + o] = f2b(fmaxf(sh + a, 0.f));
    }
}

// ---------------- fused tail ----------------
__global__ __launch_bounds__(256) void k_tail(
    const float* __restrict__ Yd, const float* __restrict__ Ys, const float* __restrict__ Yl,
    const unsigned short* __restrict__ Hyper,
    const float* __restrict__ TB0, const float* __restrict__ Tlb0,
    const float* __restrict__ Tk1, const float* __restrict__ Tb1,
    const float* __restrict__ TA1, const float* __restrict__ TB1, const float* __restrict__ Tlb1,
    const float* __restrict__ h0W, const float* __restrict__ h0b,
    const float* __restrict__ h1W, const float* __restrict__ h1b,
    float* __restrict__ out)
{
    __shared__ float sTB0[2][16][128];
    __shared__ float sTlb0[2][128];
    __shared__ float sTk1[128];
    __shared__ float sWeff[2][128];
    __shared__ float sY[4][3][160];
    const int tid = threadIdx.x;

    for (int i = tid; i < 4096; i += 256) ((float*)sTB0)[i] = TB0[i];
    if (tid < 256) ((float*)sTlb0)[tid] = Tlb0[tid];
    if (tid < 128) sTk1[tid] = Tk1[tid];
    {
        int t = tid >> 7, j = tid & 127;
        float a = 0.f;
        #pragma unroll
        for (int r = 0; r < 16; ++r) a += TA1[((size_t)t * 128 + j) * 16 + r] * TB1[t * 16 + r];
        sWeff[t][j] = a;
    }
    const float* Yp[3] = {Yd, Ys, Yl};
    int b0 = blockIdx.x * 4;
    for (int i = tid; i < 4 * 3 * 160; i += 256) {
        int s = i / 480, rem = i % 480, st = rem / 160, idx = rem % 160;
        sY[s][st][idx] = Yp[st][(size_t)(b0 + s) * 160 + idx];
    }
    __syncthreads();

    int w = tid >> 6, lane = tid & 63;
    int b = b0 + w;
    const float* yd = sY[w][0];
    const float* ys = sY[w][1];
    const float* yl = sY[w][2];
    int j0 = lane, j1 = lane + 64;

    uint4 hraw = *(const uint4*)(Hyper + (size_t)b * 512 + lane * 8);
    const unsigned short* hp = (const unsigned short*)&hraw;
    float hv[8];
    #pragma unroll
    for (int j = 0; j < 8; ++j) hv[j] = b2f(hp[j]);

    float red[14];
    #pragma unroll
    for (int k = 0; k < 14; ++k) red[k] = 0.f;
    #pragma unroll
    for (int j = 0; j < 8; ++j) {
        float4 w0 = *(const float4*)(h0W + (size_t)(lane * 8 + j) * 4);
        float4 w1 = *(const float4*)(h1W + (size_t)(lane * 8 + j) * 4);
        red[0] += hv[j] * w0.x; red[1] += hv[j] * w0.y; red[2] += hv[j] * w0.z; red[3] += hv[j] * w0.w;
        red[4] += hv[j] * w1.x; red[5] += hv[j] * w1.y; red[6] += hv[j] * w1.z; red[7] += hv[j] * w1.w;
    }

    float SLv[2][2], LSv[2][2];
    #pragma unroll
    for (int t = 0; t < 2; ++t) {
        float lb0 = sTlb0[t][j0], lb1 = sTlb0[t][j1];
        float dl0 = lb0, dl1 = lb1, sl0 = lb0, sl1 = lb1, ll0 = lb0, ll1 = lb1;
        #pragma unroll
        for (int r = 0; r < 16; ++r) {
            float w0v = sTB0[t][r][j0], w1v = sTB0[t][r][j1];
            float ud = yd[128 + t * 16 + r];
            float us = ys[128 + t * 16 + r];
            float ul = yl[128 + t * 16 + r];
            dl0 += ud * w0v; dl1 += ud * w1v;
            sl0 += us * w0v; sl1 += us * w1v;
            ll0 += ul * w0v; ll1 += ul * w1v;
        }
        float D0 = yd[j0] + dl0, D1 = yd[j1] + dl1;
        float S0 = ys[j0],       S1 = ys[j1];
        float L0 = ll0,          L1 = ll1;
        float sl_0 = sl0, sl_1 = sl1;
        float ls_0 = yl[j0], ls_1 = yl[j1];
        if (t == 0) {
            D0 = fmaxf(D0, 0.f); D1 = fmaxf(D1, 0.f);
            S0 = fmaxf(S0, 0.f); S1 = fmaxf(S1, 0.f);
            L0 = fmaxf(L0, 0.f); L1 = fmaxf(L1, 0.f);
            sl_0 = fmaxf(sl_0, 0.f); sl_1 = fmaxf(sl_1, 0.f);
            ls_0 = fmaxf(ls_0, 0.f); ls_1 = fmaxf(ls_1, 0.f);
        }
        SLv[t][0] = sl_0; SLv[t][1] = sl_1;
        LSv[t][0] = ls_0; LSv[t][1] = ls_1;
        float we0 = sWeff[t][j0], we1 = sWeff[t][j1];
        float tk0 = sTk1[j0],     tk1v = sTk1[j1];
        red[8 + t * 3 + 0] = D0 * (tk0 + we0) + D1 * (tk1v + we1);
        red[8 + t * 3 + 1] = S0 * tk0 + S1 * tk1v;
        red[8 + t * 3 + 2] = L0 * we0 + L1 * we1;
    }

    #pragma unroll
    for (int s = 1; s < 64; s <<= 1) {
        #pragma unroll
        for (int k = 0; k < 14; ++k) red[k] += __shfl_xor(red[k], s, 64);
    }

    float Tb1v = Tb1[0];
    #pragma unroll
    for (int t = 0; t < 2; ++t) {
        float fd = red[8 + t * 3 + 0] + Tb1v + Tlb1[t];
        float fs = red[8 + t * 3 + 1] + Tb1v;
        float fl = red[8 + t * 3 + 2] + Tlb1[t];
        const float* hb = t ? h1b : h0b;
        float g0 = 1.f / (1.f + expf(-(red[t * 4 + 0] + hb[0])));
        float g1 = 1.f / (1.f + expf(-(red[t * 4 + 1] + hb[1])));
        float g2 = 1.f / (1.f + expf(-(red[t * 4 + 2] + hb[2])));
        float g3 = 1.f / (1.f + expf(-(red[t * 4 + 3] + hb[3])));
        float base = fd - g0 * fs - g1 * fl;
        size_t o = (size_t)t * BATCH * 128 + (size_t)b * 128;
        out[o + j0] = base - g2 * SLv[t][0] - g3 * LSv[t][0];
        out[o + j1] = base - g2 * SLv[t][1] - g3 * LSv[t][1];
    }
}

// ---------------- host ----------------
extern "C" void kernel_launch(void* const* d_in, const int* in_sizes, int n_in,
                              void* d_out, int out_size, void* d_ws, size_t ws_size,
                              hipStream_t stream)
{
    const int*   x    = (const int*)  d_in[0];
    const int*   dix  = (const int*)  d_in[1];
    const float* emb  = (const float*)d_in[2];
    const float* sW0  = (const float*)d_in[3];
    const float* sb0  = (const float*)d_in[4];
    const float* sW1  = (const float*)d_in[5];
    const float* sb1  = (const float*)d_in[6];
    const float* Dk0  = (const float*)d_in[7];
    const float* Db0  = (const float*)d_in[8];
    const float* DA0  = (const float*)d_in[9];
    const float* DB0  = (const float*)d_in[10];
    const float* Dlb0 = (const float*)d_in[11];
    const float* Tk0  = (const float*)d_in[12];
    const float* Tb0  = (const float*)d_in[13];
    const float* Tk1  = (const float*)d_in[14];
    const float* Tb1  = (const float*)d_in[15];
    const float* TA0  = (const float*)d_in[16];
    const float* TB0  = (const float*)d_in[17];
    const float* Tlb0 = (const float*)d_in[18];
    const float* TA1  = (const float*)d_in[19];
    const float* TB1  = (const float*)d_in[20];
    const float* Tlb1 = (const float*)d_in[21];
    const float* gW0  = (const float*)d_in[22];
    const float* gb0  = (const float*)d_in[23];
    const float* gW1  = (const float*)d_in[24];
    const float* gb1  = (const float*)d_in[25];
    const float* h0W  = (const float*)d_in[26];
    const float* h0b  = (const float*)d_in[27];
    const float* h1W  = (const float*)d_in[28];
    const float* h1b  = (const float*)d_in[29];

    // allow 128 KiB dynamic LDS for the 8-phase kernel (idempotent)
    hipFuncSetAttribute((const void*)k_gemm256<1, 1>,
                        hipFuncAttributeMaxDynamicSharedMemorySize, 131072);

    char* ws = (char*)d_ws;
    size_t off = 0;
    auto alloc = [&](size_t bytes) -> void* {
        void* p = ws + off;
        off += (bytes + 255) & ~(size_t)255;
        return p;
    };
    unsigned short* W1t   = (unsigned short*)alloc((size_t)2048 * 2048 * 2);
    unsigned short* W2st  = (unsigned short*)alloc((size_t)512 * 1024 * 2);  // W2cat base
    unsigned short* W2gt  = (unsigned short*)alloc((size_t)512 * 1024 * 2);  // = W2st + 512*1024
    unsigned short* Dk0t  = (unsigned short*)alloc((size_t)256 * 512 * 2);
    unsigned short* Tcat  = (unsigned short*)alloc((size_t)160 * 256 * 2);
    float*          b1cat = (float*)alloc(2048 * 4);
    float*          b2cat = (float*)alloc(1024 * 4);
    float*          tb0c  = (float*)alloc(160 * 4);
    char* regA = (char*)alloc((size_t)BATCH * 2048 * 2);   // Xemb, later Ys/Yl/Yd
    char* regB = (char*)alloc((size_t)BATCH * 2048 * 2);   // H, later SHARE/LORA/DDNN
    unsigned short* Xdnn  = (unsigned short*)alloc((size_t)BATCH * 512 * 2);  // Hyper adjacent
    unsigned short* Hyper = (unsigned short*)alloc((size_t)BATCH * 512 * 2);

    unsigned short* Xemb = (unsigned short*)regA;
    float* Ybase = (float*)regA;
    float* Ys = Ybase;                              // stream order: SHARE, LORA, DDNN
    float* Yl = Ybase + (size_t)BATCH * 160;
    float* Yd = Ybase + (size_t)2 * BATCH * 160;
    unsigned short* Hbuf  = (unsigned short*)regB;
    unsigned short* SHARE = (unsigned short*)regB;
    unsigned short* LORA  = SHARE + (size_t)BATCH * 256;
    unsigned short* DDNN  = LORA  + (size_t)BATCH * 256;

    dim3 tb(32, 8);
    // weight prep (bf16, transposed N x K)
    k_transpose_cvt<<<dim3(32, 64), tb, 0, stream>>>(sW0, 2048, 1024, W1t, 0,    2048);
    k_transpose_cvt<<<dim3(32, 64), tb, 0, stream>>>(gW0, 2048, 1024, W1t, 1024, 2048);
    k_transpose_cvt<<<dim3(16, 32), tb, 0, stream>>>(sW1, 1024, 512, W2st, 0, 1024);
    k_transpose_cvt<<<dim3(16, 32), tb, 0, stream>>>(gW1, 1024, 512, W2gt, 0, 1024);
    k_transpose_cvt<<<dim3(8, 16),  tb, 0, stream>>>(Dk0, 512, 256, Dk0t, 0, 512);
    k_transpose_cvt<<<dim3(4, 8),   tb, 0, stream>>>(Tk0, 256, 128, Tcat, 0,   256);
    k_transpose_cvt<<<dim3(1, 8),   tb, 0, stream>>>(TA0,           256, 16, Tcat, 128, 256);
    k_transpose_cvt<<<dim3(1, 8),   tb, 0, stream>>>(TA0 + 256*16,  256, 16, Tcat, 144, 256);
    k_copyf<<<4, 256, 0, stream>>>(sb0, b1cat, 1024);
    k_copyf<<<4, 256, 0, stream>>>(gb0, b1cat + 1024, 1024);
    k_copyf<<<2, 256, 0, stream>>>(sb1, b2cat, 512);
    k_copyf<<<2, 256, 0, stream>>>(gb1, b2cat + 512, 512);
    k_copyf<<<1, 256, 0, stream>>>(Tb0, tb0c, 128);
    k_zerof<<<1, 256, 0, stream>>>(tb0c + 128, 32);

    // gather
    k_gather<<<32768, 256, 0, stream>>>(x, emb, Xemb);
    // GEMM1 (8-phase 256^2): x_emb @ [sW0|gW0], relu -> H (B,2048) bf16
    k_gemm256<1, 1><<<dim3(8, 64, 1), 512, 131072, stream>>>(
        Xemb, 2048, 0, W1t, 2048, 0, b1cat, 0, Hbuf, 2048, 0, 2048);
    // GEMM2 grouped (z=0: share-MLP, z=1: gate-hypernet): H halves -> Xdnn / Hyper
    k_gemm256<1, 1><<<dim3(2, 64, 2), 512, 131072, stream>>>(
        Hbuf, 2048, 1024, W2st, 1024, (long)512 * 1024, b2cat, 512,
        Xdnn, 512, (long)BATCH * 512, 512);
    // GEMM3: share = x_dnn @ Dk0 + Db0 (pre-act) bf16
    k_gemm<0, 1><<<dim3(2, 128), 256, 0, stream>>>(Xdnn, 512, Dk0t, Db0, SHARE, 256, 256, 512);
    // domain LoRA + ddnn
    k_dlora<<<BATCH / 4, 256, 0, stream>>>(Xdnn, dix, DA0, DB0, Dlb0, SHARE, LORA, DDNN);
    // stage i=0: one fused GEMM over 3 contiguous streams @ [Tk0|TA0[0]|TA0[1]]
    k_gemm<0, 0><<<dim3(2, 384), 256, 0, stream>>>(SHARE, 256, Tcat, tb0c, Ybase, 160, 160, 256);
    // fused tail
    k_tail<<<BATCH / 4, 256, 0, stream>>>(Yd, Ys, Yl, Hyper, TB0, Tlb0, Tk1, Tb1,
                                          TA1, TB1, Tlb1, h0W, h0b, h1W, h1b, (float*)d_out);
}

// Round 4
// 374.570 us; speedup vs baseline: 1.5468x; 1.1023x over previous
//
#include <hip/hip_runtime.h>
#include <hip/hip_bf16.h>

#define BATCH 16384

typedef __attribute__((ext_vector_type(4))) float f32x4;
typedef __attribute__((ext_vector_type(8))) short bf16x8;

__device__ inline float b2f(unsigned short u) {
    union { unsigned u; float f; } c; c.u = ((unsigned)u) << 16; return c.f;
}
__device__ inline unsigned short f2b(float f) {
    __hip_bfloat16 h = __float2bfloat16(f);
    return *(unsigned short*)&h;
}

#define GLL16(g, l)                                                            \
    __builtin_amdgcn_global_load_lds(                                          \
        (const __attribute__((address_space(1))) void*)(g),                    \
        (__attribute__((address_space(3))) void*)(l), 16, 0, 0)

// ---------------- weight prep: f32 (K x N) -> bf16 transposed (N x K), z-paired ----------------
__global__ void k_tcvt2(const float* __restrict__ src0, const float* __restrict__ src1,
                        int K, int N,
                        unsigned short* __restrict__ dst, int off0, int off1, int dst_ld)
{
    __shared__ float t[32][33];
    const float* src = blockIdx.z ? src1 : src0;
    int dst_off = blockIdx.z ? off1 : off0;
    int k0 = blockIdx.y * 32, n0 = blockIdx.x * 32;
    int tx = threadIdx.x, ty = threadIdx.y; // 32 x 8
    #pragma unroll
    for (int s = 0; s < 32; s += 8) {
        int k = k0 + ty + s, n = n0 + tx;
        t[ty + s][tx] = (k < K && n < N) ? src[(size_t)k * N + n] : 0.f;
    }
    __syncthreads();
    #pragma unroll
    for (int s = 0; s < 32; s += 8) {
        int n = n0 + ty + s, k = k0 + tx;
        if (n < N && k < K)
            dst[(size_t)(dst_off + n) * dst_ld + k] = f2b(t[tx][ty + s]);
    }
}

// ---------------- small prep: bias concats + DA0/DB0 bf16 conversion ----------------
__global__ __launch_bounds__(256) void k_smallprep(
    const float* __restrict__ sb0, const float* __restrict__ gb0,
    const float* __restrict__ sb1, const float* __restrict__ gb1,
    const float* __restrict__ Tb0,
    const float* __restrict__ DA0, const float* __restrict__ DB0,
    float* __restrict__ b1cat, float* __restrict__ b2cat, float* __restrict__ tb0c,
    unsigned short* __restrict__ DA0b, unsigned short* __restrict__ DB0b)
{
    int i = blockIdx.x * 256 + threadIdx.x;
    if (i < 1024)            { b1cat[i] = sb0[i]; return; }
    if (i < 2048)            { b1cat[i] = gb0[i - 1024]; return; }
    if (i < 2560)            { b2cat[i - 2048] = sb1[i - 2048]; return; }
    if (i < 3072)            { b2cat[i - 2560 + 512] = gb1[i - 2560]; return; }
    if (i < 3200)            { tb0c[i - 3072] = Tb0[i - 3072]; return; }
    if (i < 3232)            { tb0c[i - 3200 + 128] = 0.f; return; }
    i -= 3232;
    if (i < 65536)           { DA0b[i] = f2b(DA0[i]); return; }
    i -= 65536;
    if (i < 32768)           { DB0b[i] = f2b(DB0[i]); return; }
}

// ---------------- embedding gather -> bf16 x_emb (B, 2048) ----------------
__global__ __launch_bounds__(256) void k_gather(const int* __restrict__ x,
                                                const float* __restrict__ emb,
                                                unsigned short* __restrict__ Xemb)
{
    int i = blockIdx.x * 256 + threadIdx.x;   // group of 4 elements
    int b  = i >> 9;                          // 512 groups per row of 2048
    int j4 = (i & 511) << 2;
    int f  = j4 >> 6;
    int l  = j4 & 63;
    int idx = x[b * 32 + f];
    float4 v = *(const float4*)(emb + (size_t)idx * 64 + l);
    ushort4 o;
    o.x = f2b(v.x); o.y = f2b(v.y); o.z = f2b(v.z); o.w = f2b(v.w);
    *(ushort4*)(Xemb + (size_t)b * 2048 + j4) = o;
}

// ================= 256x256 slab-phase MFMA GEMM (T2+T4+T5, 1 barrier/slab) ====================
// C(MxN) = A(MxK)*Bt(NxK)^T + bias, opt relu. Tile 256x256, 512 thr (8 waves 2Mx4N),
// LDS ring of 4 slabs x 32KB (slab = A[256][32] + B[256][32], interleaved per 128B row:
// chunks 0-3 = A, 4-7 = B, XOR swizzle p = c ^ (row&7), both-sides).
// Per phase (one slab): STAGE slab s+3 (4 gload_lds) | 12 ds_read_b128 (compiler-
// scheduled lgkm waits interleave with MFMA) | setprio(1) 32 MFMA setprio(0) |
// vmcnt(8) (slab s+1 published) | s_barrier.  vmcnt never 0 in the loop (T4).
template<int RELU, int OUTBF16>
__global__ __launch_bounds__(512, 2) void k_gemm256(
    const unsigned short* __restrict__ A, int lda, long Az,
    const unsigned short* __restrict__ Bt, int K, long Bz,
    const float* __restrict__ bias, int biasz,
    void* __restrict__ C, int ldc, long Cz,
    int N)
{
    extern __shared__ char smem_raw[];
    const int NS = K >> 5;            // 32-wide K slabs
    const int tid  = threadIdx.x;
    const int lane = tid & 63;
    const int w    = tid >> 6;
    const int wr   = w >> 2, wc = w & 3;
    const int frow = lane & 15, kg = lane >> 4;
    const int z = blockIdx.z;
    A    += (size_t)z * Az;
    Bt   += (size_t)z * Bz;
    bias += (size_t)z * biasz;

    // XCD-aware bijective swizzle (nwg divisible by 8 for all our launches)
    const int gx  = gridDim.x;
    const int nwg = gx * gridDim.y;
    const int lin = blockIdx.y * gx + blockIdx.x;
    const int qq  = nwg >> 3;
    const int swz = (lin & 7) * qq + (lin >> 3);
    const int bx = swz % gx, by = swz / gx;
    const int row0 = by * 256, col0 = bx * 256;

    // staging sources (full slab = 4 x 8KB rounds, idx = h*2+r2), per-lane pre-swizzled
    const int lch = (tid & 7) ^ ((tid >> 3) & 7);   // logical chunk this lane feeds
    const unsigned short* gsrc[4];
    int dOff[4];
    #pragma unroll
    for (int h = 0; h < 2; ++h)
        #pragma unroll
        for (int r2 = 0; r2 < 2; ++r2) {
            int rr = h * 128 + r2 * 64 + (tid >> 3);   // row in slab
            const unsigned short* p;
            if (lch < 4) p = A  + (size_t)(row0 + rr) * lda + lch * 8;
            else         p = Bt + (size_t)min(col0 + rr, N - 1) * K + (lch - 4) * 8;
            gsrc[h * 2 + r2] = p;
            dOff[h * 2 + r2] = h * 16384 + r2 * 8192 + w * 1024;   // wave-uniform LDS base
        }

    // fragment read offsets (bytes) within a slab; swizzled physical chunks
    const int pA = kg ^ (frow & 7);
    const int pB = (4 + kg) ^ (frow & 7);
    int aOff[8], bOff[4];
    #pragma unroll
    for (int m = 0; m < 8; ++m) aOff[m] = (wr * 128 + m * 16 + frow) * 128 + pA * 16;
    #pragma unroll
    for (int n = 0; n < 4; ++n) bOff[n] = (wc * 64 + n * 16 + frow) * 128 + pB * 16;

#define STAGE(sIdx) do {                                                         \
        int rp_ = (sIdx) & 3;                                                    \
        int s_  = min((int)(sIdx), NS - 1);                                      \
        GLL16(gsrc[0] + s_ * 32, smem_raw + rp_ * 32768 + dOff[0]);              \
        GLL16(gsrc[1] + s_ * 32, smem_raw + rp_ * 32768 + dOff[1]);              \
        GLL16(gsrc[2] + s_ * 32, smem_raw + rp_ * 32768 + dOff[2]);              \
        GLL16(gsrc[3] + s_ * 32, smem_raw + rp_ * 32768 + dOff[3]);              \
    } while (0)

    f32x4 acc[8][4] = {};

    // prologue: slabs 0,1,2 -> slots 0,1,2 ; publish slab 0
    STAGE(0); STAGE(1); STAGE(2);
    asm volatile("s_waitcnt vmcnt(8)" ::: "memory");
    __builtin_amdgcn_s_barrier();

    for (int s = 0; s < NS; ++s) {
        const char* sb = smem_raw + (s & 3) * 32768;
        STAGE(s + 3);                      // into slot (s-1)&3, readers done last phase
        bf16x8 bfr[4], afr[8];
        #pragma unroll
        for (int n = 0; n < 4; ++n) bfr[n] = *(const bf16x8*)(sb + bOff[n]);
        #pragma unroll
        for (int m = 0; m < 8; ++m) afr[m] = *(const bf16x8*)(sb + aOff[m]);
        __builtin_amdgcn_s_setprio(1);
        #pragma unroll
        for (int m = 0; m < 8; ++m)
            #pragma unroll
            for (int n = 0; n < 4; ++n)
                acc[m][n] = __builtin_amdgcn_mfma_f32_16x16x32_bf16(afr[m], bfr[n], acc[m][n], 0, 0, 0);
        __builtin_amdgcn_s_setprio(0);
        asm volatile("s_waitcnt vmcnt(8)" ::: "memory");   // slab s+1 published for ALL waves
        __builtin_amdgcn_s_barrier();
    }
#undef STAGE

    // epilogue: C/D layout col=lane&15, row=(lane>>4)*4+reg
    #pragma unroll
    for (int n = 0; n < 4; ++n) {
        int gcol = col0 + wc * 64 + n * 16 + frow;
        if (gcol >= N) continue;
        float bv = bias[gcol];
        #pragma unroll
        for (int m = 0; m < 8; ++m) {
            int gr = row0 + wr * 128 + m * 16 + kg * 4;
            #pragma unroll
            for (int r = 0; r < 4; ++r) {
                float v = acc[m][n][r] + bv;
                if (RELU) v = fmaxf(v, 0.f);
                size_t idx = (size_t)(gr + r) * ldc + gcol;
                if (OUTBF16) ((unsigned short*)C + (size_t)z * Cz)[idx] = f2b(v);
                else         ((float*)C + (size_t)z * Cz)[idx] = v;
            }
        }
    }
}

// ---------------- 128x128 MFMA GEMM (m97 structure) for small GEMMs ----------------
template<int RELU, int OUTBF16>
__global__ __launch_bounds__(256) void k_gemm(
    const unsigned short* __restrict__ A, int lda,
    const unsigned short* __restrict__ Bt,         // N x K row-major, ldb = K
    const float* __restrict__ bias,
    void* __restrict__ C, int ldc,
    int N, int K)
{
    __shared__ __align__(16) unsigned short As[128 * 32];
    __shared__ __align__(16) unsigned short Bs[128 * 32];
    const int tid  = threadIdx.x;
    const int lane = tid & 63;
    const int w    = tid >> 6;
    const int wr   = w >> 1, wc = w & 1;
    const int row0 = blockIdx.y * 128;
    const int col0 = blockIdx.x * 128;
    const int frow = lane & 15;
    const int kg   = lane >> 4;
    const int sw   = kg ^ ((frow >> 1) & 3);

    const int srow = w * 32 + (lane >> 2);
    const int csw  = (lane & 3) ^ ((lane >> 3) & 3);
    const int br0  = min(col0 + srow, N - 1);
    const int br1  = min(col0 + srow + 16, N - 1);

    const unsigned short* a0 = A  + (size_t)(row0 + srow) * lda      + csw * 8;
    const unsigned short* a1 = A  + (size_t)(row0 + srow + 16) * lda + csw * 8;
    const unsigned short* b0 = Bt + (size_t)br0 * K + csw * 8;
    const unsigned short* b1 = Bt + (size_t)br1 * K + csw * 8;
    unsigned short* lA0 = As + (w * 2 + 0) * 512;
    unsigned short* lA1 = As + (w * 2 + 1) * 512;
    unsigned short* lB0 = Bs + (w * 2 + 0) * 512;
    unsigned short* lB1 = Bs + (w * 2 + 1) * 512;

    f32x4 acc[4][4] = {};

    for (int bk = 0; bk < K; bk += 32) {
        __syncthreads();
        GLL16(a0 + bk, lA0);
        GLL16(a1 + bk, lA1);
        GLL16(b0 + bk, lB0);
        GLL16(b1 + bk, lB1);
        __syncthreads();
        bf16x8 af[4], bfr[4];
        #pragma unroll
        for (int m = 0; m < 4; ++m)
            af[m] = *(const bf16x8*)&As[(wr * 64 + m * 16 + frow) * 32 + sw * 8];
        #pragma unroll
        for (int n = 0; n < 4; ++n)
            bfr[n] = *(const bf16x8*)&Bs[(wc * 64 + n * 16 + frow) * 32 + sw * 8];
        #pragma unroll
        for (int m = 0; m < 4; ++m)
            #pragma unroll
            for (int n = 0; n < 4; ++n)
                acc[m][n] = __builtin_amdgcn_mfma_f32_16x16x32_bf16(af[m], bfr[n], acc[m][n], 0, 0, 0);
    }

    #pragma unroll
    for (int n = 0; n < 4; ++n) {
        int gcol = col0 + wc * 64 + n * 16 + frow;
        if (gcol >= N) continue;
        float bv = bias[gcol];
        #pragma unroll
        for (int m = 0; m < 4; ++m) {
            int gr = row0 + wr * 64 + m * 16 + kg * 4;
            #pragma unroll
            for (int r = 0; r < 4; ++r) {
                float v = acc[m][n][r] + bv;
                if (RELU) v = fmaxf(v, 0.f);
                size_t idx = (size_t)(gr + r) * ldc + gcol;
                if (OUTBF16) ((unsigned short*)C)[idx] = f2b(v);
                else         ((float*)C)[idx] = v;
            }
        }
    }
}

// ---------------- per-sample domain LoRA (bf16 weights) ----------------
__global__ __launch_bounds__(256) void k_dlora(
    const unsigned short* __restrict__ Xdnn, const int* __restrict__ d,
    const unsigned short* __restrict__ DA0b, const unsigned short* __restrict__ DB0b,
    const float* __restrict__ Dlb0,
    const unsigned short* __restrict__ SHARE,
    unsigned short* __restrict__ LORA, unsigned short* __restrict__ DDNN)
{
    int w = threadIdx.x >> 6, lane = threadIdx.x & 63;
    int b = blockIdx.x * 4 + w;
    int dom = d[b];
    uint4 raw = *(const uint4*)(Xdnn + (size_t)b * 512 + lane * 8);
    const unsigned short* pr = (const unsigned short*)&raw;
    float xv[8];
    #pragma unroll
    for (int j = 0; j < 8; ++j) xv[j] = b2f(pr[j]);

    const unsigned short* Ap = DA0b + ((size_t)dom * 512 + lane * 8) * 16;
    float v[16];
    #pragma unroll
    for (int r = 0; r < 16; ++r) v[r] = 0.f;
    #pragma unroll
    for (int j = 0; j < 8; ++j) {
        uint4 a0 = *(const uint4*)(Ap + j * 16);
        uint4 a1 = *(const uint4*)(Ap + j * 16 + 8);
        const unsigned short* ap = (const unsigned short*)&a0;
        const unsigned short* aq = (const unsigned short*)&a1;
        float xj = xv[j];
        #pragma unroll
        for (int r = 0; r < 8; ++r) v[r]     += xj * b2f(ap[r]);
        #pragma unroll
        for (int r = 0; r < 8; ++r) v[r + 8] += xj * b2f(aq[r]);
    }
    #pragma unroll
    for (int s = 1; s < 64; s <<= 1) {
        #pragma unroll
        for (int r = 0; r < 16; ++r) v[r] += __shfl_xor(v[r], s, 64);
    }
    const unsigned short* Bp = DB0b + (size_t)dom * 16 * 256;
    const float* lbp = Dlb0 + (size_t)dom * 256;
    #pragma unroll
    for (int c = 0; c < 4; ++c) {
        int o = lane + c * 64;
        float a = lbp[o];
        #pragma unroll
        for (int r = 0; r < 16; ++r) a += v[r] * b2f(Bp[r * 256 + o]);
        float sh = b2f(SHARE[(size_t)b * 256 + o]);
        LORA[(size_t)b * 256 + o] = f2b(a);
        DDNN[(size_t)b * 256 + o] = f2b(fmaxf(sh + a, 0.f));
    }
}

// ---------------- fused tail ----------------
__global__ __launch_bounds__(256) void k_tail(
    const float* __restrict__ Yd, const float* __restrict__ Ys, const float* __restrict__ Yl,
    const unsigned short* __restrict__ Hyper,
    const float* __restrict__ TB0, const float* __restrict__ Tlb0,
    const float* __restrict__ Tk1, const float* __restrict__ Tb1,
    const float* __restrict__ TA1, const float* __restrict__ TB1, const float* __restrict__ Tlb1,
    const float* __restrict__ h0W, const float* __restrict__ h0b,
    const float* __restrict__ h1W, const float* __restrict__ h1b,
    float* __restrict__ out)
{
    __shared__ float sTB0[2][16][128];
    __shared__ float sTlb0[2][128];
    __shared__ float sTk1[128];
    __shared__ float sWeff[2][128];
    __shared__ float sY[4][3][160];
    const int tid = threadIdx.x;

    for (int i = tid; i < 4096; i += 256) ((float*)sTB0)[i] = TB0[i];
    if (tid < 256) ((float*)sTlb0)[tid] = Tlb0[tid];
    if (tid < 128) sTk1[tid] = Tk1[tid];
    {
        int t = tid >> 7, j = tid & 127;
        float a = 0.f;
        #pragma unroll
        for (int r = 0; r < 16; ++r) a += TA1[((size_t)t * 128 + j) * 16 + r] * TB1[t * 16 + r];
        sWeff[t][j] = a;
    }
    const float* Yp[3] = {Yd, Ys, Yl};
    int b0 = blockIdx.x * 4;
    for (int i = tid; i < 4 * 3 * 160; i += 256) {
        int s = i / 480, rem = i % 480, st = rem / 160, idx = rem % 160;
        sY[s][st][idx] = Yp[st][(size_t)(b0 + s) * 160 + idx];
    }
    __syncthreads();

    int w = tid >> 6, lane = tid & 63;
    int b = b0 + w;
    const float* yd = sY[w][0];
    const float* ys = sY[w][1];
    const float* yl = sY[w][2];
    int j0 = lane, j1 = lane + 64;

    uint4 hraw = *(const uint4*)(Hyper + (size_t)b * 512 + lane * 8);
    const unsigned short* hp = (const unsigned short*)&hraw;
    float hv[8];
    #pragma unroll
    for (int j = 0; j < 8; ++j) hv[j] = b2f(hp[j]);

    float red[14];
    #pragma unroll
    for (int k = 0; k < 14; ++k) red[k] = 0.f;
    #pragma unroll
    for (int j = 0; j < 8; ++j) {
        float4 w0 = *(const float4*)(h0W + (size_t)(lane * 8 + j) * 4);
        float4 w1 = *(const float4*)(h1W + (size_t)(lane * 8 + j) * 4);
        red[0] += hv[j] * w0.x; red[1] += hv[j] * w0.y; red[2] += hv[j] * w0.z; red[3] += hv[j] * w0.w;
        red[4] += hv[j] * w1.x; red[5] += hv[j] * w1.y; red[6] += hv[j] * w1.z; red[7] += hv[j] * w1.w;
    }

    float SLv[2][2], LSv[2][2];
    #pragma unroll
    for (int t = 0; t < 2; ++t) {
        float lb0 = sTlb0[t][j0], lb1 = sTlb0[t][j1];
        float dl0 = lb0, dl1 = lb1, sl0 = lb0, sl1 = lb1, ll0 = lb0, ll1 = lb1;
        #pragma unroll
        for (int r = 0; r < 16; ++r) {
            float w0v = sTB0[t][r][j0], w1v = sTB0[t][r][j1];
            float ud = yd[128 + t * 16 + r];
            float us = ys[128 + t * 16 + r];
            float ul = yl[128 + t * 16 + r];
            dl0 += ud * w0v; dl1 += ud * w1v;
            sl0 += us * w0v; sl1 += us * w1v;
            ll0 += ul * w0v; ll1 += ul * w1v;
        }
        float D0 = yd[j0] + dl0, D1 = yd[j1] + dl1;
        float S0 = ys[j0],       S1 = ys[j1];
        float L0 = ll0,          L1 = ll1;
        float sl_0 = sl0, sl_1 = sl1;
        float ls_0 = yl[j0], ls_1 = yl[j1];
        if (t == 0) {
            D0 = fmaxf(D0, 0.f); D1 = fmaxf(D1, 0.f);
            S0 = fmaxf(S0, 0.f); S1 = fmaxf(S1, 0.f);
            L0 = fmaxf(L0, 0.f); L1 = fmaxf(L1, 0.f);
            sl_0 = fmaxf(sl_0, 0.f); sl_1 = fmaxf(sl_1, 0.f);
            ls_0 = fmaxf(ls_0, 0.f); ls_1 = fmaxf(ls_1, 0.f);
        }
        SLv[t][0] = sl_0; SLv[t][1] = sl_1;
        LSv[t][0] = ls_0; LSv[t][1] = ls_1;
        float we0 = sWeff[t][j0], we1 = sWeff[t][j1];
        float tk0 = sTk1[j0],     tk1v = sTk1[j1];
        red[8 + t * 3 + 0] = D0 * (tk0 + we0) + D1 * (tk1v + we1);
        red[8 + t * 3 + 1] = S0 * tk0 + S1 * tk1v;
        red[8 + t * 3 + 2] = L0 * we0 + L1 * we1;
    }

    #pragma unroll
    for (int s = 1; s < 64; s <<= 1) {
        #pragma unroll
        for (int k = 0; k < 14; ++k) red[k] += __shfl_xor(red[k], s, 64);
    }

    float Tb1v = Tb1[0];
    #pragma unroll
    for (int t = 0; t < 2; ++t) {
        float fd = red[8 + t * 3 + 0] + Tb1v + Tlb1[t];
        float fs = red[8 + t * 3 + 1] + Tb1v;
        float fl = red[8 + t * 3 + 2] + Tlb1[t];
        const float* hb = t ? h1b : h0b;
        float g0 = 1.f / (1.f + expf(-(red[t * 4 + 0] + hb[0])));
        float g1 = 1.f / (1.f + expf(-(red[t * 4 + 1] + hb[1])));
        float g2 = 1.f / (1.f + expf(-(red[t * 4 + 2] + hb[2])));
        float g3 = 1.f / (1.f + expf(-(red[t * 4 + 3] + hb[3])));
        float base = fd - g0 * fs - g1 * fl;
        size_t o = (size_t)t * BATCH * 128 + (size_t)b * 128;
        out[o + j0] = base - g2 * SLv[t][0] - g3 * LSv[t][0];
        out[o + j1] = base - g2 * SLv[t][1] - g3 * LSv[t][1];
    }
}

// ---------------- host ----------------
extern "C" void kernel_launch(void* const* d_in, const int* in_sizes, int n_in,
                              void* d_out, int out_size, void* d_ws, size_t ws_size,
                              hipStream_t stream)
{
    const int*   x    = (const int*)  d_in[0];
    const int*   dix  = (const int*)  d_in[1];
    const float* emb  = (const float*)d_in[2];
    const float* sW0  = (const float*)d_in[3];
    const float* sb0  = (const float*)d_in[4];
    const float* sW1  = (const float*)d_in[5];
    const float* sb1  = (const float*)d_in[6];
    const float* Dk0  = (const float*)d_in[7];
    const float* Db0  = (const float*)d_in[8];
    const float* DA0  = (const float*)d_in[9];
    const float* DB0  = (const float*)d_in[10];
    const float* Dlb0 = (const float*)d_in[11];
    const float* Tk0  = (const float*)d_in[12];
    const float* Tb0  = (const float*)d_in[13];
    const float* Tk1  = (const float*)d_in[14];
    const float* Tb1  = (const float*)d_in[15];
    const float* TA0  = (const float*)d_in[16];
    const float* TB0  = (const float*)d_in[17];
    const float* Tlb0 = (const float*)d_in[18];
    const float* TA1  = (const float*)d_in[19];
    const float* TB1  = (const float*)d_in[20];
    const float* Tlb1 = (const float*)d_in[21];
    const float* gW0  = (const float*)d_in[22];
    const float* gb0  = (const float*)d_in[23];
    const float* gW1  = (const float*)d_in[24];
    const float* gb1  = (const float*)d_in[25];
    const float* h0W  = (const float*)d_in[26];
    const float* h0b  = (const float*)d_in[27];
    const float* h1W  = (const float*)d_in[28];
    const float* h1b  = (const float*)d_in[29];

    hipFuncSetAttribute((const void*)k_gemm256<1, 1>,
                        hipFuncAttributeMaxDynamicSharedMemorySize, 131072);

    char* ws = (char*)d_ws;
    size_t off = 0;
    auto alloc = [&](size_t bytes) -> void* {
        void* p = ws + off;
        off += (bytes + 255) & ~(size_t)255;
        return p;
    };
    unsigned short* W1t   = (unsigned short*)alloc((size_t)2048 * 2048 * 2);
    unsigned short* W2cat = (unsigned short*)alloc((size_t)1024 * 1024 * 2); // rows 0-511 share, 512-1023 gate
    unsigned short* Dk0t  = (unsigned short*)alloc((size_t)256 * 512 * 2);
    unsigned short* Tcat  = (unsigned short*)alloc((size_t)160 * 256 * 2);
    unsigned short* DA0b  = (unsigned short*)alloc((size_t)8 * 512 * 16 * 2);
    unsigned short* DB0b  = (unsigned short*)alloc((size_t)8 * 16 * 256 * 2);
    float*          b1cat = (float*)alloc(2048 * 4);
    float*          b2cat = (float*)alloc(1024 * 4);
    float*          tb0c  = (float*)alloc(160 * 4);
    char* regA = (char*)alloc((size_t)BATCH * 2048 * 2);   // Xemb, later Ys/Yl/Yd
    char* regB = (char*)alloc((size_t)BATCH * 2048 * 2);   // H, later SHARE/LORA/DDNN
    unsigned short* Xdnn  = (unsigned short*)alloc((size_t)BATCH * 512 * 2);
    unsigned short* Hyper = (unsigned short*)alloc((size_t)BATCH * 512 * 2);

    unsigned short* Xemb = (unsigned short*)regA;
    float* Ybase = (float*)regA;
    float* Ys = Ybase;                              // stream order: SHARE, LORA, DDNN
    float* Yl = Ybase + (size_t)BATCH * 160;
    float* Yd = Ybase + (size_t)2 * BATCH * 160;
    unsigned short* Hbuf  = (unsigned short*)regB;
    unsigned short* SHARE = (unsigned short*)regB;
    unsigned short* LORA  = SHARE + (size_t)BATCH * 256;
    unsigned short* DDNN  = LORA  + (size_t)BATCH * 256;

    dim3 tb(32, 8);
    // weight prep (bf16, transposed N x K) — paired launches
    k_tcvt2<<<dim3(32, 64, 2), tb, 0, stream>>>(sW0, gW0, 2048, 1024, W1t, 0, 1024, 2048);
    k_tcvt2<<<dim3(16, 32, 2), tb, 0, stream>>>(sW1, gW1, 1024, 512, W2cat, 0, 512, 1024);
    k_tcvt2<<<dim3(8, 16, 1),  tb, 0, stream>>>(Dk0, Dk0, 512, 256, Dk0t, 0, 0, 512);
    k_tcvt2<<<dim3(4, 8, 1),   tb, 0, stream>>>(Tk0, Tk0, 256, 128, Tcat, 0, 0, 256);
    k_tcvt2<<<dim3(1, 8, 2),   tb, 0, stream>>>(TA0, TA0 + 256 * 16, 256, 16, Tcat, 128, 144, 256);
    k_smallprep<<<397, 256, 0, stream>>>(sb0, gb0, sb1, gb1, Tb0, DA0, DB0,
                                         b1cat, b2cat, tb0c, DA0b, DB0b);

    // gather
    k_gather<<<32768, 256, 0, stream>>>(x, emb, Xemb);
    // GEMM1 (slab-phase 256^2): x_emb @ [sW0|gW0], relu -> H (B,2048) bf16
    k_gemm256<1, 1><<<dim3(8, 64, 1), 512, 131072, stream>>>(
        Xemb, 2048, 0, W1t, 2048, 0, b1cat, 0, Hbuf, 2048, 0, 2048);
    // GEMM2 grouped (z=0: share-MLP, z=1: gate-hypernet): H halves -> Xdnn / Hyper
    k_gemm256<1, 1><<<dim3(2, 64, 2), 512, 131072, stream>>>(
        Hbuf, 2048, 1024, W2cat, 1024, (long)512 * 1024, b2cat, 512,
        Xdnn, 512, (long)BATCH * 512, 512);
    // GEMM3: share = x_dnn @ Dk0 + Db0 (pre-act) bf16
    k_gemm<0, 1><<<dim3(2, 128), 256, 0, stream>>>(Xdnn, 512, Dk0t, Db0, SHARE, 256, 256, 512);
    // domain LoRA + ddnn
    k_dlora<<<BATCH / 4, 256, 0, stream>>>(Xdnn, dix, DA0b, DB0b, Dlb0, SHARE, LORA, DDNN);
    // stage i=0: one fused GEMM over 3 contiguous streams @ [Tk0|TA0[0]|TA0[1]]
    k_gemm<0, 0><<<dim3(2, 384), 256, 0, stream>>>(SHARE, 256, Tcat, tb0c, Ybase, 160, 160, 256);
    // fused tail
    k_tail<<<BATCH / 4, 256, 0, stream>>>(Yd, Ys, Yl, Hyper, TB0, Tlb0, Tk1, Tb1,
                                          TA1, TB1, Tlb1, h0W, h0b, h1W, h1b, (float*)d_out);
}